// Round 2
// baseline (740.604 us; speedup 1.0000x reference)
//
#include <hip/hip_runtime.h>
#include <hip/hip_bf16.h>

#define N_NODES 50000
#define N_EDGES 800000
#define SCAN_NB ((N_NODES + 1023) / 1024)   // 49

// ---------- helpers ----------
__device__ __forceinline__ float rdlane(float v, int k) {
    return __uint_as_float(__builtin_amdgcn_readlane(__float_as_uint(v), k));
}
template <int CTRL>
__device__ __forceinline__ float dpp_addf(float v) {
    int x = __builtin_amdgcn_update_dpp(0, __float_as_int(v), CTRL, 0xF, 0xF, true);
    return v + __int_as_float(x);
}
#define DPP_QX1  0xB1   // quad_perm [1,0,3,2]
#define DPP_QX2  0x4E   // quad_perm [2,3,0,1]
#define DPP_HM   0x141  // row_half_mirror
#define DPP_RM   0x140  // row_mirror
#define DPP_ROR4 0x124  // row_ror:4
#define DPP_ROR8 0x128  // row_ror:8
__device__ __forceinline__ float dpp_sum16(float v) {
    v = dpp_addf<DPP_QX1>(v);
    v = dpp_addf<DPP_QX2>(v);
    v = dpp_addf<DPP_HM>(v);
    v = dpp_addf<DPP_RM>(v);
    return v;
}
__device__ __forceinline__ void bsum4(float& v0, float& v1, float& v2, float& v3) {
    #pragma unroll
    for (int m = 1; m < 64; m <<= 1) {
        v0 += __shfl_xor(v0, m);
        v1 += __shfl_xor(v1, m);
        v2 += __shfl_xor(v2, m);
        v3 += __shfl_xor(v3, m);
    }
}

// ---------- setup ----------
// fused: h = x@in_w+in_b ; xcur=x ; cntC=0 ; layer-0 t = h@rw1[:64]+rb1 (readlane GEMM)
__global__ void k_h01(const float* __restrict__ x, const float* __restrict__ in_w,
                      const float* __restrict__ in_b, const float* __restrict__ rw1,
                      const float* __restrict__ rb1, float* __restrict__ hb,
                      float4* __restrict__ xcur, unsigned* __restrict__ cntC,
                      float* __restrict__ t) {
    int tid = threadIdx.x;
    int wid = (blockIdx.x * blockDim.x + tid) >> 6;
    int lane = tid & 63;
    int n0 = wid * 4;
    if (n0 >= N_NODES) return;
    float iw0 = in_w[lane], iw1 = in_w[64 + lane], iw2 = in_w[128 + lane], iw3 = in_w[192 + lane];
    float ibl = in_b[lane];
    float hv[4];
    #pragma unroll
    for (int i = 0; i < 4; i++) {
        int n = n0 + i;
        hv[i] = 0.f;
        if (n < N_NODES) {
            float4 xv = ((const float4*)x)[n];
            hv[i] = ibl + xv.x * iw0 + xv.y * iw1 + xv.z * iw2 + xv.w * iw3;
            hb[n * 64 + lane] = hv[i];
            if (lane == 0) { xcur[n] = xv; cntC[n] = 0u; }
        }
    }
    float acc[4];
    #pragma unroll
    for (int i = 0; i < 4; i++) acc[i] = rb1[lane];
    for (int k = 0; k < 64; k++) {
        float w = rw1[k * 64 + lane];
        #pragma unroll
        for (int i = 0; i < 4; i++) acc[i] += rdlane(hv[i], k) * w;
    }
    #pragma unroll
    for (int i = 0; i < 4; i++) {
        int n = n0 + i;
        if (n < N_NODES) t[n * 64 + lane] = acc[i];
    }
}

// col-side only: count + per-edge rank
__global__ void k_count(const int* __restrict__ col, unsigned* __restrict__ cntC,
                        unsigned* __restrict__ rankC) {
    int e = blockIdx.x * blockDim.x + threadIdx.x;
    if (e < N_EDGES) rankC[e] = atomicAdd(&cntC[col[e]], 1u);
}

__global__ void __launch_bounds__(1024) k_scanA(const unsigned* __restrict__ cntC,
                                                unsigned* __restrict__ offsC,
                                                float* __restrict__ deg,
                                                unsigned* __restrict__ bs1) {
    __shared__ unsigned s1[1024];
    int tid = threadIdx.x;
    int i = blockIdx.x * 1024 + tid;
    unsigned v1 = (i < N_NODES) ? cntC[i] : 0u;
    s1[tid] = v1;
    __syncthreads();
    for (int off = 1; off < 1024; off <<= 1) {
        unsigned t1 = (tid >= off) ? s1[tid - off] : 0u;
        __syncthreads();
        s1[tid] += t1;
        __syncthreads();
    }
    if (i < N_NODES) {
        offsC[i] = s1[tid] - v1;
        deg[i]   = (float)(v1 + 1u);   // + self loop
    }
    if (tid == 1023) bs1[blockIdx.x] = s1[1023];
}

__global__ void k_scanB(const unsigned* __restrict__ bs1, unsigned* __restrict__ carry1,
                        unsigned* __restrict__ offsC) {
    int lane = threadIdx.x;  // 64 threads
    unsigned v1 = (lane < SCAN_NB) ? bs1[lane] : 0u;
    unsigned i1 = v1;
    #pragma unroll
    for (int off = 1; off < 64; off <<= 1) {
        unsigned t1 = __shfl_up(i1, off);
        if (lane >= off) i1 += t1;
    }
    if (lane < SCAN_NB) carry1[lane] = i1 - v1;
    if (lane == SCAN_NB - 1) offsC[N_NODES] = i1;
}

__global__ void __launch_bounds__(1024) k_scanC(unsigned* __restrict__ offsC,
                                                const unsigned* __restrict__ carry1) {
    int b = blockIdx.x;
    int i = b * 1024 + threadIdx.x;
    if (i < N_NODES) offsC[i] += carry1[b];
}

// pure write phase: one packed 16B record per col-slot: {ea0, ea1, src}
__global__ void k_write(const int* __restrict__ row, const int* __restrict__ col,
                        const float* __restrict__ ea,
                        const unsigned* __restrict__ offsC, const unsigned* __restrict__ rankC,
                        float4* __restrict__ colEA) {
    int e = blockIdx.x * blockDim.x + threadIdx.x;
    if (e >= N_EDGES) return;
    int r = row[e], c = col[e];
    float2 e2 = ((const float2*)ea)[e];
    colEA[offsC[c] + rankC[e]] = make_float4(e2.x, e2.y, __int_as_float(r), 0.f);
}

// merged per-layer constants: blocks 0-3 score (M,u,v,w), blocks 4-7 value (Wp,bp)
__global__ void k_prep2(const float* __restrict__ qw, const float* __restrict__ qb,
                        const float* __restrict__ kw, const float* __restrict__ kb,
                        const float* __restrict__ vw, const float* __restrict__ vb,
                        const float* __restrict__ ow, float* __restrict__ cst,
                        float* __restrict__ cstV) {
    int m = threadIdx.x;
    int d = m & 15;
    if (blockIdx.x < 4) {
        int L = blockIdx.x;
        const float* qwl = qw + L * 256; const float* kwl = kw + L * 256;
        const float* qbl = qb + L * 64;  const float* kbl = kb + L * 64;
        float qa[4], ka[4];
        #pragma unroll
        for (int a = 0; a < 4; a++) { qa[a] = qwl[a * 64 + m]; ka[a] = kwl[a * 64 + m]; }
        float qbm = qbl[m], kbm = kbl[m];
        float vals[25];
        int idx = 0;
        #pragma unroll
        for (int a = 0; a < 4; a++)
            #pragma unroll
            for (int b = 0; b < 4; b++) vals[idx++] = qa[a] * ka[b];
        #pragma unroll
        for (int a = 0; a < 4; a++) vals[idx++] = qa[a] * kbm;
        #pragma unroll
        for (int b = 0; b < 4; b++) vals[idx++] = qbm * ka[b];
        vals[24] = qbm * kbm;
        #pragma unroll
        for (int i = 0; i < 25; i++) {
            float v = vals[i];
            v += __shfl_xor(v, 1); v += __shfl_xor(v, 2);
            v += __shfl_xor(v, 4); v += __shfl_xor(v, 8);
            vals[i] = v;
        }
        if (d == 0) {
            float* out = cst + L * 128 + (m >> 4) * 32;
            #pragma unroll
            for (int i = 0; i < 25; i++) out[i] = vals[i] * 0.25f;
        }
    } else {
        int L = blockIdx.x - 4;
        int h = m >> 4;
        const float* vwl = vw + L * 256;
        const float* vbl = vb + L * 64;
        float4 owv = ((const float4*)(ow + L * 256))[m];
        float vals[20];
        #pragma unroll
        for (int a = 0; a < 4; a++) {
            float v = vwl[a * 64 + m];
            vals[a * 4 + 0] = v * owv.x; vals[a * 4 + 1] = v * owv.y;
            vals[a * 4 + 2] = v * owv.z; vals[a * 4 + 3] = v * owv.w;
        }
        float b = vbl[m];
        vals[16] = b * owv.x; vals[17] = b * owv.y; vals[18] = b * owv.z; vals[19] = b * owv.w;
        #pragma unroll
        for (int i = 0; i < 20; i++) {
            float v = vals[i];
            v += __shfl_xor(v, 1); v += __shfl_xor(v, 2);
            v += __shfl_xor(v, 4); v += __shfl_xor(v, 8);
            vals[i] = v;
        }
        if (d == 0) {
            float* out = cstV + L * 128 + h * 32;
            #pragma unroll
            for (int i = 0; i < 20; i++) out[i] = vals[i];
        }
    }
}

// ---------- per-layer ----------
// layers 1..3: finalize prev layer, write h, compute this layer's t (readlane GEMM)
__global__ void k61(const float* __restrict__ att16, const float* __restrict__ sumexp,
                    const float4* __restrict__ x4b, const float* __restrict__ ob,
                    const float* __restrict__ g, const float* __restrict__ bb,
                    const float* __restrict__ resw, const float* __restrict__ in_w,
                    const float* __restrict__ in_b, float4* __restrict__ xcur,
                    const float* __restrict__ rw1, const float* __restrict__ rb1,
                    float* __restrict__ t, float* __restrict__ hb) {
    int tid = threadIdx.x;
    int wid = (blockIdx.x * blockDim.x + tid) >> 6;
    int lane = tid & 63;
    int n0 = wid * 4;
    if (n0 >= N_NODES) return;
    float iw0 = in_w[lane], iw1 = in_w[64 + lane], iw2 = in_w[128 + lane], iw3 = in_w[192 + lane];
    float ibl = in_b[lane];
    float z = sumexp[(lane & 15) >> 2];
    float ob0 = ob[0], ob1 = ob[1], ob2 = ob[2], ob3 = ob[3];
    float g0 = g[0], g1 = g[1], g2 = g[2], g3 = g[3];
    float bb0 = bb[0], bb1 = bb[1], bb2 = bb[2], bb3 = bb[3];
    float rw = resw[0];
    float hv[4];
    #pragma unroll
    for (int i = 0; i < 4; i++) {
        int n = n0 + i;
        float a = 0.f;
        if (n < N_NODES && lane < 16) a = att16[n * 16 + lane] / z;
        a = dpp_addf<DPP_ROR4>(a);
        a = dpp_addf<DPP_ROR8>(a);
        float y0 = rdlane(a, 0), y1 = rdlane(a, 1), y2 = rdlane(a, 2), y3 = rdlane(a, 3);
        hv[i] = 0.f;
        if (n < N_NODES) {
            float4 x4v = x4b[n];
            y0 += ob0 + x4v.x; y1 += ob1 + x4v.y;
            y2 += ob2 + x4v.z; y3 += ob3 + x4v.w;
            float mu = 0.25f * (y0 + y1 + y2 + y3);
            float d0 = y0 - mu, d1 = y1 - mu, d2 = y2 - mu, d3 = y3 - mu;
            float var = 0.25f * (d0 * d0 + d1 * d1 + d2 * d2 + d3 * d3);
            float rs = rsqrtf(var + 1e-5f);
            float4 xold = xcur[n];
            float nn0 = d0 * rs * g0 + bb0 + xold.x * rw;
            float nn1 = d1 * rs * g1 + bb1 + xold.y * rw;
            float nn2 = d2 * rs * g2 + bb2 + xold.z * rw;
            float nn3 = d3 * rs * g3 + bb3 + xold.w * rw;
            if (lane == 0) xcur[n] = make_float4(nn0, nn1, nn2, nn3);
            hv[i] = ibl + nn0 * iw0 + nn1 * iw1 + nn2 * iw2 + nn3 * iw3;
            hb[n * 64 + lane] = hv[i];
        }
    }
    float acc[4];
    #pragma unroll
    for (int i = 0; i < 4; i++) acc[i] = rb1[lane];
    for (int k = 0; k < 64; k++) {
        float w = rw1[k * 64 + lane];
        #pragma unroll
        for (int i = 0; i < 4; i++) acc[i] += rdlane(hv[i], k) * w;
    }
    #pragma unroll
    for (int i = 0; i < 4; i++) {
        int n = n0 + i;
        if (n < N_NODES) t[n * 64 + lane] = acc[i];
    }
}

// fused msg-compute + gather + self-loop + base + x4: quarter-wave per dst.
// Batched 4 edges/iter, 3-stage pipeline: compute batch A while 4 t-rows (B)
// and 4 records (C) are in flight -> ~8 outstanding loads per 16-lane group.
__global__ void k23b(const unsigned* __restrict__ offsC, const float4* __restrict__ colEA,
                     const float* __restrict__ t, const float* __restrict__ hb,
                     const float* __restrict__ rw1, const float* __restrict__ rw2,
                     const float* __restrict__ sw, const float* __restrict__ rb2,
                     const float* __restrict__ sb, const float* __restrict__ deg,
                     float4* __restrict__ x4b, float* __restrict__ sumexp) {
    __shared__ float s_rw2[64][4];
    __shared__ float s_sw[64][4];
    __shared__ float s_w1[128];
    int tid = threadIdx.x;
    { int r = tid >> 2, cc = tid & 3; s_rw2[r][cc] = rw2[r * 64 + cc]; s_sw[r][cc] = sw[r * 256 + cc]; }
    if (tid < 128) s_w1[tid] = rw1[64 * 64 + tid];
    if (blockIdx.x == 0 && tid < 4) sumexp[tid] = 0.f;
    __syncthreads();
    int lane = tid & 63;
    int sub = lane >> 4, l16 = lane & 15;
    int gid = (blockIdx.x * blockDim.x + tid) >> 6;
    int c = gid * 4 + sub;
    if (c >= N_NODES) return;
    // per-lane weights for fixed channels ch = l16*4 + j
    float w1a[4], w1b[4], wr2[4][4];
    #pragma unroll
    for (int j = 0; j < 4; j++) {
        int ch = l16 * 4 + j;
        w1a[j] = s_w1[ch];
        w1b[j] = s_w1[64 + ch];
        #pragma unroll
        for (int o = 0; o < 4; o++) wr2[j][o] = s_rw2[ch][o];
    }
    const float4* t4g = (const float4*)t;
    float4 tv = t4g[c * 16 + l16];
    float4 hv = ((const float4*)hb)[c * 16 + l16];
    float a0 = 0.f, a1 = 0.f, a2 = 0.f, a3 = 0.f;
    float b0 = 0.f, b1 = 0.f, b2 = 0.f, b3 = 0.f;
    #pragma unroll
    for (int j = 0; j < 4; j++) {
        int ch = l16 * 4 + j;
        float tk = (j == 0) ? tv.x : (j == 1) ? tv.y : (j == 2) ? tv.z : tv.w;
        float rr = fmaxf(tk, 0.f);   // self loop: ea = 0
        a0 += rr * wr2[j][0]; a1 += rr * wr2[j][1];
        a2 += rr * wr2[j][2]; a3 += rr * wr2[j][3];
        float hk = (j == 0) ? hv.x : (j == 1) ? hv.y : (j == 2) ? hv.z : hv.w;
        b0 += hk * s_sw[ch][0]; b1 += hk * s_sw[ch][1];
        b2 += hk * s_sw[ch][2]; b3 += hk * s_sw[ch][3];
    }
    int beg = (int)offsC[c], end = (int)offsC[c + 1];
    const float4 z4 = make_float4(0.f, 0.f, 0.f, 0.f);
    float4 erA[4], tvA[4], erB[4];
    int p = beg;
    #pragma unroll
    for (int i = 0; i < 4; i++) erA[i] = (p + i < end) ? colEA[p + i] : z4;
    #pragma unroll
    for (int i = 0; i < 4; i++)
        tvA[i] = (p + i < end) ? t4g[__float_as_int(erA[i].z) * 16 + l16] : z4;
    #pragma unroll
    for (int i = 0; i < 4; i++) erB[i] = (p + 4 + i < end) ? colEA[p + 4 + i] : z4;
    while (p < end) {
        float4 tvB[4];
        #pragma unroll
        for (int i = 0; i < 4; i++)
            tvB[i] = (p + 4 + i < end) ? t4g[__float_as_int(erB[i].z) * 16 + l16] : z4;
        float4 erC[4];
        #pragma unroll
        for (int i = 0; i < 4; i++) erC[i] = (p + 8 + i < end) ? colEA[p + 8 + i] : z4;
        #pragma unroll
        for (int i = 0; i < 4; i++) {
            float ex = erA[i].x, ey = erA[i].y;
            #pragma unroll
            for (int j = 0; j < 4; j++) {
                float tk = (j == 0) ? tvA[i].x : (j == 1) ? tvA[i].y : (j == 2) ? tvA[i].z : tvA[i].w;
                float pre = tk + ex * w1a[j] + ey * w1b[j];
                float rr = fmaxf(pre, 0.f);
                a0 += rr * wr2[j][0]; a1 += rr * wr2[j][1];
                a2 += rr * wr2[j][2]; a3 += rr * wr2[j][3];
            }
        }
        #pragma unroll
        for (int i = 0; i < 4; i++) { erA[i] = erB[i]; tvA[i] = tvB[i]; erB[i] = erC[i]; }
        p += 4;
    }
    a0 = dpp_sum16(a0); a1 = dpp_sum16(a1); a2 = dpp_sum16(a2); a3 = dpp_sum16(a3);
    b0 = dpp_sum16(b0); b1 = dpp_sum16(b1); b2 = dpp_sum16(b2); b3 = dpp_sum16(b3);
    if (l16 == 0) {
        float idg = 1.f / deg[c];
        x4b[c] = make_float4(a0 * idg + b0 + rb2[0] + sb[0],
                             a1 * idg + b1 + rb2[1] + sb[1],
                             a2 * idg + b2 + rb2[2] + sb[2],
                             a3 * idg + b3 + rb2[3] + sb[3]);
    }
}

// attention gather, rank-4-factored V; WAVE per dst.
// Each 16-lane sub handles TWO slots per iter (p, p+4; stride 8), 2-batch-ahead
// src prefetch -> 2x in-flight x4b loads vs previous version.
__global__ void k5_att(const unsigned* __restrict__ offsC, const float4* __restrict__ colEA,
                       const float4* __restrict__ x4b, const float* __restrict__ cst,
                       const float* __restrict__ cstV, float* __restrict__ att16,
                       float* __restrict__ zbuf) {
    int tid = threadIdx.x;
    int lane = tid & 63;
    int sub = lane >> 4, d = lane & 15, h = d >> 2, a = d & 3;
    const float* C = cst + h * 32;
    int c = (blockIdx.x * blockDim.x + tid) >> 6;   // wave per dst
    if (c >= N_NODES) return;
    float4 xc = x4b[c];
    float g0 = xc.x * C[0]  + xc.y * C[1]  + xc.z * C[2]  + xc.w * C[3]  + C[16];
    float g1 = xc.x * C[4]  + xc.y * C[5]  + xc.z * C[6]  + xc.w * C[7]  + C[17];
    float g2 = xc.x * C[8]  + xc.y * C[9]  + xc.z * C[10] + xc.w * C[11] + C[18];
    float g3 = xc.x * C[12] + xc.y * C[13] + xc.z * C[14] + xc.w * C[15] + C[19];
    float base = C[20] * xc.x + C[21] * xc.y + C[22] * xc.z + C[23] * xc.w + C[24];
    int beg = (int)offsC[c], end = (int)offsC[c + 1];
    const float* cE = (const float*)colEA;
    const float4 z4 = make_float4(0.f, 0.f, 0.f, 0.f);
    float S = 0.f, z = 0.f;
    int p = beg + sub;
    bool vA0 = p < end, vA1 = p + 4 < end;
    int sA0 = vA0 ? __float_as_int(cE[4 * p + 2]) : 0;
    int sA1 = vA1 ? __float_as_int(cE[4 * (p + 4) + 2]) : 0;
    float4 xA0 = vA0 ? x4b[sA0] : z4;
    float4 xA1 = vA1 ? x4b[sA1] : z4;
    bool vB0 = p + 8 < end, vB1 = p + 12 < end;
    int sB0 = vB0 ? __float_as_int(cE[4 * (p + 8) + 2]) : 0;
    int sB1 = vB1 ? __float_as_int(cE[4 * (p + 12) + 2]) : 0;
    while (vA0) {
        float4 xB0 = vB0 ? x4b[sB0] : z4;
        float4 xB1 = vB1 ? x4b[sB1] : z4;
        bool vC0 = p + 16 < end, vC1 = p + 20 < end;
        int sC0 = vC0 ? __float_as_int(cE[4 * (p + 16) + 2]) : 0;
        int sC1 = vC1 ? __float_as_int(cE[4 * (p + 20) + 2]) : 0;
        {
            float s = xA0.x * g0 + xA0.y * g1 + xA0.z * g2 + xA0.w * g3 + base;
            float ex = __expf(s);
            float xa = (a == 0) ? xA0.x : (a == 1) ? xA0.y : (a == 2) ? xA0.z : xA0.w;
            S += ex * xa;
            z += ex;
        }
        if (vA1) {
            float s = xA1.x * g0 + xA1.y * g1 + xA1.z * g2 + xA1.w * g3 + base;
            float ex = __expf(s);
            float xa = (a == 0) ? xA1.x : (a == 1) ? xA1.y : (a == 2) ? xA1.z : xA1.w;
            S += ex * xa;
            z += ex;
        }
        xA0 = xB0; xA1 = xB1; vA0 = vB0; vA1 = vB1;
        sB0 = sC0; sB1 = sC1; vB0 = vC0; vB1 = vC1;
        p += 8;
    }
    S += __shfl_xor(S, 16); S += __shfl_xor(S, 32);
    z += __shfl_xor(z, 16); z += __shfl_xor(z, 32);
    const float* V = cstV + h * 32;
    float c0 = S * V[a * 4 + 0], c1 = S * V[a * 4 + 1];
    float c2 = S * V[a * 4 + 2], c3 = S * V[a * 4 + 3];
    c0 = dpp_addf<DPP_QX1>(c0); c1 = dpp_addf<DPP_QX1>(c1);
    c2 = dpp_addf<DPP_QX1>(c2); c3 = dpp_addf<DPP_QX1>(c3);
    c0 = dpp_addf<DPP_QX2>(c0); c1 = dpp_addf<DPP_QX2>(c1);
    c2 = dpp_addf<DPP_QX2>(c2); c3 = dpp_addf<DPP_QX2>(c3);
    float my = (a == 0) ? c0 : (a == 1) ? c1 : (a == 2) ? c2 : c3;
    if (sub == 0) {
        att16[c * 16 + d] = my + z * V[16 + a];
        if (a == 0) zbuf[c * 4 + h] = z;
    }
}

// reduce zbuf (N_NODES x 4) -> sumexp[4]; LDS block reduction, 49 atomics per head
__global__ void __launch_bounds__(1024) k_zred(const float4* __restrict__ zbuf,
                                               float* __restrict__ sumexp) {
    __shared__ float s[16][4];
    int tid = threadIdx.x;
    int i = blockIdx.x * 1024 + tid;
    float4 v = make_float4(0.f, 0.f, 0.f, 0.f);
    if (i < N_NODES) v = zbuf[i];
    bsum4(v.x, v.y, v.z, v.w);
    int w = tid >> 6;
    if ((tid & 63) == 0) { s[w][0] = v.x; s[w][1] = v.y; s[w][2] = v.z; s[w][3] = v.w; }
    __syncthreads();
    if (tid < 4) {
        float acc = 0.f;
        #pragma unroll
        for (int ww = 0; ww < 16; ww++) acc += s[ww][tid];
        atomicAdd(&sumexp[tid], acc);
    }
}

// final: finalize layer 3 then MLP head (readlane GEMM)
__global__ void k6pred(const float* __restrict__ att16, const float* __restrict__ sumexp,
                       const float4* __restrict__ x4b, const float* __restrict__ ob,
                       const float* __restrict__ g, const float* __restrict__ bb,
                       const float* __restrict__ resw, const float4* __restrict__ xcur,
                       const float* __restrict__ in_w, const float* __restrict__ in_b,
                       const float* __restrict__ w1, const float* __restrict__ b1,
                       const float* __restrict__ w2, const float* __restrict__ b2,
                       float* __restrict__ out) {
    int tid = threadIdx.x;
    int node = (blockIdx.x * blockDim.x + tid) >> 6;
    int lane = tid & 63;
    if (node >= N_NODES) return;
    float z = sumexp[(lane & 15) >> 2];
    float a = 0.f;
    if (lane < 16) a = att16[node * 16 + lane] / z;
    a = dpp_addf<DPP_ROR4>(a);
    a = dpp_addf<DPP_ROR8>(a);
    float y0 = rdlane(a, 0), y1 = rdlane(a, 1), y2 = rdlane(a, 2), y3 = rdlane(a, 3);
    float4 x4v = x4b[node];
    y0 += ob[0] + x4v.x; y1 += ob[1] + x4v.y;
    y2 += ob[2] + x4v.z; y3 += ob[3] + x4v.w;
    float mu = 0.25f * (y0 + y1 + y2 + y3);
    float d0 = y0 - mu, d1 = y1 - mu, d2 = y2 - mu, d3 = y3 - mu;
    float var = 0.25f * (d0 * d0 + d1 * d1 + d2 * d2 + d3 * d3);
    float rs = rsqrtf(var + 1e-5f);
    float4 xold = xcur[node];
    float rw = resw[0];
    float n0 = d0 * rs * g[0] + bb[0] + xold.x * rw;
    float n1 = d1 * rs * g[1] + bb[1] + xold.y * rw;
    float n2 = d2 * rs * g[2] + bb[2] + xold.z * rw;
    float n3 = d3 * rs * g[3] + bb[3] + xold.w * rw;
    float hv = in_b[lane] + n0 * in_w[lane] + n1 * in_w[64 + lane]
             + n2 * in_w[128 + lane] + n3 * in_w[192 + lane];
    int j2 = lane & 31;
    float m = b1[j2];
    for (int k = 0; k < 64; k++) m += rdlane(hv, k) * w1[k * 32 + j2];
    m = fmaxf(m, 0.f);
    float4 w2v = ((const float4*)w2)[j2];
    float v0 = m * w2v.x, v1 = m * w2v.y, v2 = m * w2v.z, v3 = m * w2v.w;
    bsum4(v0, v1, v2, v3);  // each j2 counted twice (both halves) -> *0.5
    float o0 = tanhf(0.5f * v0 + b2[0]) * 0.3f;
    float o1 = tanhf(0.5f * v1 + b2[1]) * 0.3f;
    float o2 = tanhf(0.5f * v2 + b2[2]) * 0.3f;
    float o3 = tanhf(0.5f * v3 + b2[3]) * 0.3f;
    if (lane == 0) ((float4*)out)[node] = make_float4(o0, o1, o2, o3);
}

// ---------- launch ----------
extern "C" void kernel_launch(void* const* d_in, const int* in_sizes, int n_in,
                              void* d_out, int out_size, void* d_ws, size_t ws_size,
                              hipStream_t stream) {
    const float* x        = (const float*)d_in[0];
    const int*   ei       = (const int*)d_in[1];
    const float* ea       = (const float*)d_in[2];
    const float* in_w     = (const float*)d_in[3];
    const float* in_b     = (const float*)d_in[4];
    const float* conv_rw1 = (const float*)d_in[5];
    const float* conv_rb1 = (const float*)d_in[6];
    const float* conv_rw2 = (const float*)d_in[7];
    const float* conv_rb2 = (const float*)d_in[8];
    // d_in[9..12] (imag path) dead: x4 = h4[:, :4] only touches real[:, :4]
    const float* conv_sw  = (const float*)d_in[13];
    const float* conv_sb  = (const float*)d_in[14];
    const float* att_qw   = (const float*)d_in[15];
    const float* att_qb   = (const float*)d_in[16];
    const float* att_kw   = (const float*)d_in[17];
    const float* att_kb   = (const float*)d_in[18];
    const float* att_vw   = (const float*)d_in[19];
    const float* att_vb   = (const float*)d_in[20];
    const float* att_ow   = (const float*)d_in[21];
    const float* att_ob   = (const float*)d_in[22];
    const float* ln_g     = (const float*)d_in[23];
    const float* ln_b     = (const float*)d_in[24];
    const float* out_w1   = (const float*)d_in[25];
    const float* out_b1   = (const float*)d_in[26];
    const float* out_w2   = (const float*)d_in[27];
    const float* out_b2   = (const float*)d_in[28];
    const float* res_w    = (const float*)d_in[29];

    const int* row = ei;
    const int* col = ei + N_EDGES;

    char* ws = (char*)d_ws;
    size_t off = 0;
    auto alloc = [&](size_t bytes) -> void* {
        void* p = ws + off;
        off = (off + bytes + 255) & ~(size_t)255;
        return p;
    };
    float*    deg      = (float*)alloc(N_NODES * 4);
    unsigned* cntC     = (unsigned*)alloc(N_NODES * 4);
    unsigned* offsC    = (unsigned*)alloc((N_NODES + 1) * 4);
    unsigned* bs1      = (unsigned*)alloc(SCAN_NB * 4);
    unsigned* carry1   = (unsigned*)alloc(SCAN_NB * 4);
    unsigned* rankC    = (unsigned*)alloc((size_t)N_EDGES * 4);
    float4*   colEA    = (float4*)alloc((size_t)N_EDGES * 16);
    float*    tbuf     = (float*)alloc((size_t)N_NODES * 64 * 4);
    float*    hb       = (float*)alloc((size_t)N_NODES * 64 * 4);
    float*    att16    = (float*)alloc((size_t)N_NODES * 16 * 4);
    float*    zbuf     = (float*)alloc((size_t)N_NODES * 4 * 4);
    float4*   x4b      = (float4*)alloc((size_t)N_NODES * 16);
    float4*   xcur     = (float4*)alloc((size_t)N_NODES * 16);
    float*    cst      = (float*)alloc(4 * 128 * 4);
    float*    cstV     = (float*)alloc(4 * 128 * 4);
    float*    sumexp   = (float*)alloc(256);

    dim3 b256(256);
    int nodeBlocks  = (N_NODES + 3) / 4;        // wave per node
    int nodeBlocks4 = (N_NODES + 15) / 16;      // wave per 4 nodes
    int edgeTB      = (N_EDGES + 255) / 256;    // thread per edge
    int dstBlocks   = (N_NODES + 15) / 16;      // quarter-wave per dst
    int zredBlocks  = (N_NODES + 1023) / 1024;

    k_h01<<<nodeBlocks4, b256, 0, stream>>>(x, in_w, in_b, conv_rw1, conv_rb1,
                                            hb, xcur, cntC, tbuf);
    k_count<<<edgeTB, b256, 0, stream>>>(col, cntC, rankC);
    k_scanA<<<SCAN_NB, 1024, 0, stream>>>(cntC, offsC, deg, bs1);
    k_scanB<<<1, 64, 0, stream>>>(bs1, carry1, offsC);
    k_scanC<<<SCAN_NB, 1024, 0, stream>>>(offsC, carry1);
    k_write<<<edgeTB, b256, 0, stream>>>(row, col, ea, offsC, rankC, colEA);
    k_prep2<<<8, 64, 0, stream>>>(att_qw, att_qb, att_kw, att_kb,
                                  att_vw, att_vb, att_ow, cst, cstV);

    for (int i = 0; i < 4; i++) {
        const float* rw1 = conv_rw1 + i * 66 * 64;
        const float* rb1 = conv_rb1 + i * 64;
        const float* rw2 = conv_rw2 + i * 64 * 64;
        const float* rb2 = conv_rb2 + i * 64;
        const float* swl = conv_sw + i * 64 * 256;
        const float* sbl = conv_sb + i * 256;

        if (i > 0) {
            k61<<<nodeBlocks4, b256, 0, stream>>>(att16, sumexp, x4b,
                                                  att_ob + (i - 1) * 4, ln_g + (i - 1) * 4,
                                                  ln_b + (i - 1) * 4, res_w + (i - 1),
                                                  in_w, in_b, xcur,
                                                  rw1, rb1, tbuf, hb);
        }
        k23b<<<dstBlocks, b256, 0, stream>>>(offsC, colEA, tbuf, hb,
                                             rw1, rw2, swl, rb2, sbl, deg, x4b, sumexp);
        k5_att<<<nodeBlocks, b256, 0, stream>>>(offsC, colEA, x4b, cst + i * 128,
                                                cstV + i * 128, att16, zbuf);
        k_zred<<<zredBlocks, 1024, 0, stream>>>((const float4*)zbuf, sumexp);
    }
    k6pred<<<nodeBlocks, b256, 0, stream>>>(att16, sumexp, x4b, att_ob + 12, ln_g + 12,
                                            ln_b + 12, res_w + 3, xcur, in_w, in_b,
                                            out_w1, out_b1, out_w2, out_b2, (float*)d_out);
}

// Round 3
// 619.954 us; speedup vs baseline: 1.1946x; 1.1946x over previous
//
#include <hip/hip_runtime.h>
#include <hip/hip_bf16.h>

#define N_NODES 50000
#define N_EDGES 800000
#define SCAN_NB ((N_NODES + 1023) / 1024)   // 49

// ---------- helpers ----------
__device__ __forceinline__ float rdlane(float v, int k) {
    return __uint_as_float(__builtin_amdgcn_readlane(__float_as_uint(v), k));
}
template <int CTRL>
__device__ __forceinline__ float dpp_addf(float v) {
    int x = __builtin_amdgcn_update_dpp(0, __float_as_int(v), CTRL, 0xF, 0xF, true);
    return v + __int_as_float(x);
}
#define DPP_QX1  0xB1   // quad_perm [1,0,3,2]
#define DPP_QX2  0x4E   // quad_perm [2,3,0,1]
#define DPP_HM   0x141  // row_half_mirror
#define DPP_RM   0x140  // row_mirror
#define DPP_ROR4 0x124  // row_ror:4
#define DPP_ROR8 0x128  // row_ror:8
__device__ __forceinline__ float dpp_sum16(float v) {
    v = dpp_addf<DPP_QX1>(v);
    v = dpp_addf<DPP_QX2>(v);
    v = dpp_addf<DPP_HM>(v);
    v = dpp_addf<DPP_RM>(v);
    return v;
}
__device__ __forceinline__ void bsum4(float& v0, float& v1, float& v2, float& v3) {
    #pragma unroll
    for (int m = 1; m < 64; m <<= 1) {
        v0 += __shfl_xor(v0, m);
        v1 += __shfl_xor(v1, m);
        v2 += __shfl_xor(v2, m);
        v3 += __shfl_xor(v3, m);
    }
}

// ---------- setup ----------
// fused: h = x@in_w+in_b ; xcur=x ; cntC=0 ; layer-0 t = h@rw1[:64]+rb1 (readlane GEMM)
__global__ void k_h01(const float* __restrict__ x, const float* __restrict__ in_w,
                      const float* __restrict__ in_b, const float* __restrict__ rw1,
                      const float* __restrict__ rb1, float* __restrict__ hb,
                      float4* __restrict__ xcur, unsigned* __restrict__ cntC,
                      float* __restrict__ t) {
    int tid = threadIdx.x;
    int wid = (blockIdx.x * blockDim.x + tid) >> 6;
    int lane = tid & 63;
    int n0 = wid * 4;
    if (n0 >= N_NODES) return;
    float iw0 = in_w[lane], iw1 = in_w[64 + lane], iw2 = in_w[128 + lane], iw3 = in_w[192 + lane];
    float ibl = in_b[lane];
    float hv[4];
    #pragma unroll
    for (int i = 0; i < 4; i++) {
        int n = n0 + i;
        hv[i] = 0.f;
        if (n < N_NODES) {
            float4 xv = ((const float4*)x)[n];
            hv[i] = ibl + xv.x * iw0 + xv.y * iw1 + xv.z * iw2 + xv.w * iw3;
            hb[n * 64 + lane] = hv[i];
            if (lane == 0) { xcur[n] = xv; cntC[n] = 0u; }
        }
    }
    float acc[4];
    #pragma unroll
    for (int i = 0; i < 4; i++) acc[i] = rb1[lane];
    for (int k = 0; k < 64; k++) {
        float w = rw1[k * 64 + lane];
        #pragma unroll
        for (int i = 0; i < 4; i++) acc[i] += rdlane(hv[i], k) * w;
    }
    #pragma unroll
    for (int i = 0; i < 4; i++) {
        int n = n0 + i;
        if (n < N_NODES) t[n * 64 + lane] = acc[i];
    }
}

// col-side only: count + per-edge rank
__global__ void k_count(const int* __restrict__ col, unsigned* __restrict__ cntC,
                        unsigned* __restrict__ rankC) {
    int e = blockIdx.x * blockDim.x + threadIdx.x;
    if (e < N_EDGES) rankC[e] = atomicAdd(&cntC[col[e]], 1u);
}

__global__ void __launch_bounds__(1024) k_scanA(const unsigned* __restrict__ cntC,
                                                unsigned* __restrict__ offsC,
                                                float* __restrict__ deg,
                                                unsigned* __restrict__ bs1) {
    __shared__ unsigned s1[1024];
    int tid = threadIdx.x;
    int i = blockIdx.x * 1024 + tid;
    unsigned v1 = (i < N_NODES) ? cntC[i] : 0u;
    s1[tid] = v1;
    __syncthreads();
    for (int off = 1; off < 1024; off <<= 1) {
        unsigned t1 = (tid >= off) ? s1[tid - off] : 0u;
        __syncthreads();
        s1[tid] += t1;
        __syncthreads();
    }
    if (i < N_NODES) {
        offsC[i] = s1[tid] - v1;
        deg[i]   = (float)(v1 + 1u);   // + self loop
    }
    if (tid == 1023) bs1[blockIdx.x] = s1[1023];
}

__global__ void k_scanB(const unsigned* __restrict__ bs1, unsigned* __restrict__ carry1,
                        unsigned* __restrict__ offsC) {
    int lane = threadIdx.x;  // 64 threads
    unsigned v1 = (lane < SCAN_NB) ? bs1[lane] : 0u;
    unsigned i1 = v1;
    #pragma unroll
    for (int off = 1; off < 64; off <<= 1) {
        unsigned t1 = __shfl_up(i1, off);
        if (lane >= off) i1 += t1;
    }
    if (lane < SCAN_NB) carry1[lane] = i1 - v1;
    if (lane == SCAN_NB - 1) offsC[N_NODES] = i1;
}

__global__ void __launch_bounds__(1024) k_scanC(unsigned* __restrict__ offsC,
                                                const unsigned* __restrict__ carry1) {
    int b = blockIdx.x;
    int i = b * 1024 + threadIdx.x;
    if (i < N_NODES) offsC[i] += carry1[b];
}

// pure write phase: one packed 16B record per col-slot: {ea0, ea1, src}
__global__ void k_write(const int* __restrict__ row, const int* __restrict__ col,
                        const float* __restrict__ ea,
                        const unsigned* __restrict__ offsC, const unsigned* __restrict__ rankC,
                        float4* __restrict__ colEA) {
    int e = blockIdx.x * blockDim.x + threadIdx.x;
    if (e >= N_EDGES) return;
    int r = row[e], c = col[e];
    float2 e2 = ((const float2*)ea)[e];
    colEA[offsC[c] + rankC[e]] = make_float4(e2.x, e2.y, __int_as_float(r), 0.f);
}

// merged per-layer constants: blocks 0-3 score (M,u,v,w), blocks 4-7 value (Wp,bp)
__global__ void k_prep2(const float* __restrict__ qw, const float* __restrict__ qb,
                        const float* __restrict__ kw, const float* __restrict__ kb,
                        const float* __restrict__ vw, const float* __restrict__ vb,
                        const float* __restrict__ ow, float* __restrict__ cst,
                        float* __restrict__ cstV) {
    int m = threadIdx.x;
    int d = m & 15;
    if (blockIdx.x < 4) {
        int L = blockIdx.x;
        const float* qwl = qw + L * 256; const float* kwl = kw + L * 256;
        const float* qbl = qb + L * 64;  const float* kbl = kb + L * 64;
        float qa[4], ka[4];
        #pragma unroll
        for (int a = 0; a < 4; a++) { qa[a] = qwl[a * 64 + m]; ka[a] = kwl[a * 64 + m]; }
        float qbm = qbl[m], kbm = kbl[m];
        float vals[25];
        int idx = 0;
        #pragma unroll
        for (int a = 0; a < 4; a++)
            #pragma unroll
            for (int b = 0; b < 4; b++) vals[idx++] = qa[a] * ka[b];
        #pragma unroll
        for (int a = 0; a < 4; a++) vals[idx++] = qa[a] * kbm;
        #pragma unroll
        for (int b = 0; b < 4; b++) vals[idx++] = qbm * ka[b];
        vals[24] = qbm * kbm;
        #pragma unroll
        for (int i = 0; i < 25; i++) {
            float v = vals[i];
            v += __shfl_xor(v, 1); v += __shfl_xor(v, 2);
            v += __shfl_xor(v, 4); v += __shfl_xor(v, 8);
            vals[i] = v;
        }
        if (d == 0) {
            float* out = cst + L * 128 + (m >> 4) * 32;
            #pragma unroll
            for (int i = 0; i < 25; i++) out[i] = vals[i] * 0.25f;
        }
    } else {
        int L = blockIdx.x - 4;
        int h = m >> 4;
        const float* vwl = vw + L * 256;
        const float* vbl = vb + L * 64;
        float4 owv = ((const float4*)(ow + L * 256))[m];
        float vals[20];
        #pragma unroll
        for (int a = 0; a < 4; a++) {
            float v = vwl[a * 64 + m];
            vals[a * 4 + 0] = v * owv.x; vals[a * 4 + 1] = v * owv.y;
            vals[a * 4 + 2] = v * owv.z; vals[a * 4 + 3] = v * owv.w;
        }
        float b = vbl[m];
        vals[16] = b * owv.x; vals[17] = b * owv.y; vals[18] = b * owv.z; vals[19] = b * owv.w;
        #pragma unroll
        for (int i = 0; i < 20; i++) {
            float v = vals[i];
            v += __shfl_xor(v, 1); v += __shfl_xor(v, 2);
            v += __shfl_xor(v, 4); v += __shfl_xor(v, 8);
            vals[i] = v;
        }
        if (d == 0) {
            float* out = cstV + L * 128 + h * 32;
            #pragma unroll
            for (int i = 0; i < 20; i++) out[i] = vals[i];
        }
    }
}

// ---------- per-layer ----------
// layers 1..3: finalize prev layer, write h, compute this layer's t (readlane GEMM)
__global__ void k61(const float* __restrict__ att16, const float* __restrict__ sumexp,
                    const float4* __restrict__ x4b, const float* __restrict__ ob,
                    const float* __restrict__ g, const float* __restrict__ bb,
                    const float* __restrict__ resw, const float* __restrict__ in_w,
                    const float* __restrict__ in_b, float4* __restrict__ xcur,
                    const float* __restrict__ rw1, const float* __restrict__ rb1,
                    float* __restrict__ t, float* __restrict__ hb) {
    int tid = threadIdx.x;
    int wid = (blockIdx.x * blockDim.x + tid) >> 6;
    int lane = tid & 63;
    int n0 = wid * 4;
    if (n0 >= N_NODES) return;
    float iw0 = in_w[lane], iw1 = in_w[64 + lane], iw2 = in_w[128 + lane], iw3 = in_w[192 + lane];
    float ibl = in_b[lane];
    float z = sumexp[(lane & 15) >> 2];
    float ob0 = ob[0], ob1 = ob[1], ob2 = ob[2], ob3 = ob[3];
    float g0 = g[0], g1 = g[1], g2 = g[2], g3 = g[3];
    float bb0 = bb[0], bb1 = bb[1], bb2 = bb[2], bb3 = bb[3];
    float rw = resw[0];
    float hv[4];
    #pragma unroll
    for (int i = 0; i < 4; i++) {
        int n = n0 + i;
        float a = 0.f;
        if (n < N_NODES && lane < 16) a = att16[n * 16 + lane] / z;
        a = dpp_addf<DPP_ROR4>(a);
        a = dpp_addf<DPP_ROR8>(a);
        float y0 = rdlane(a, 0), y1 = rdlane(a, 1), y2 = rdlane(a, 2), y3 = rdlane(a, 3);
        hv[i] = 0.f;
        if (n < N_NODES) {
            float4 x4v = x4b[n];
            y0 += ob0 + x4v.x; y1 += ob1 + x4v.y;
            y2 += ob2 + x4v.z; y3 += ob3 + x4v.w;
            float mu = 0.25f * (y0 + y1 + y2 + y3);
            float d0 = y0 - mu, d1 = y1 - mu, d2 = y2 - mu, d3 = y3 - mu;
            float var = 0.25f * (d0 * d0 + d1 * d1 + d2 * d2 + d3 * d3);
            float rs = rsqrtf(var + 1e-5f);
            float4 xold = xcur[n];
            float nn0 = d0 * rs * g0 + bb0 + xold.x * rw;
            float nn1 = d1 * rs * g1 + bb1 + xold.y * rw;
            float nn2 = d2 * rs * g2 + bb2 + xold.z * rw;
            float nn3 = d3 * rs * g3 + bb3 + xold.w * rw;
            if (lane == 0) xcur[n] = make_float4(nn0, nn1, nn2, nn3);
            hv[i] = ibl + nn0 * iw0 + nn1 * iw1 + nn2 * iw2 + nn3 * iw3;
            hb[n * 64 + lane] = hv[i];
        }
    }
    float acc[4];
    #pragma unroll
    for (int i = 0; i < 4; i++) acc[i] = rb1[lane];
    for (int k = 0; k < 64; k++) {
        float w = rw1[k * 64 + lane];
        #pragma unroll
        for (int i = 0; i < 4; i++) acc[i] += rdlane(hv[i], k) * w;
    }
    #pragma unroll
    for (int i = 0; i < 4; i++) {
        int n = n0 + i;
        if (n < N_NODES) t[n * 64 + lane] = acc[i];
    }
}

// fused msg-compute + gather + self-loop + base + x4: quarter-wave per dst.
// 2 edges/iter, 2-stage pipeline sized to stay in registers (~90 VGPR):
// in flight per 16-lane group: 2 t-rows + 2 records ahead of compute.
// launch_bounds(256,4) -> 128-VGPR cap, no spill (round-2 4-wide spilled at 64).
__global__ void __launch_bounds__(256, 4)
k23b(const unsigned* __restrict__ offsC, const float4* __restrict__ colEA,
     const float* __restrict__ t, const float* __restrict__ hb,
     const float* __restrict__ rw1, const float* __restrict__ rw2,
     const float* __restrict__ sw, const float* __restrict__ rb2,
     const float* __restrict__ sb, const float* __restrict__ deg,
     float4* __restrict__ x4b, float* __restrict__ sumexp) {
    __shared__ float s_rw2[64][4];
    __shared__ float s_sw[64][4];
    __shared__ float s_w1[128];
    int tid = threadIdx.x;
    { int r = tid >> 2, cc = tid & 3; s_rw2[r][cc] = rw2[r * 64 + cc]; s_sw[r][cc] = sw[r * 256 + cc]; }
    if (tid < 128) s_w1[tid] = rw1[64 * 64 + tid];
    if (blockIdx.x == 0 && tid < 4) sumexp[tid] = 0.f;
    __syncthreads();
    int lane = tid & 63;
    int sub = lane >> 4, l16 = lane & 15;
    int gid = (blockIdx.x * blockDim.x + tid) >> 6;
    int c = gid * 4 + sub;
    if (c >= N_NODES) return;
    // per-lane weights for fixed channels ch = l16*4 + j
    float w1a[4], w1b[4], wr2[4][4];
    #pragma unroll
    for (int j = 0; j < 4; j++) {
        int ch = l16 * 4 + j;
        w1a[j] = s_w1[ch];
        w1b[j] = s_w1[64 + ch];
        #pragma unroll
        for (int o = 0; o < 4; o++) wr2[j][o] = s_rw2[ch][o];
    }
    const float4* t4g = (const float4*)t;
    float4 tv = t4g[c * 16 + l16];
    float4 hv = ((const float4*)hb)[c * 16 + l16];
    float a0 = 0.f, a1 = 0.f, a2 = 0.f, a3 = 0.f;
    float b0 = 0.f, b1 = 0.f, b2 = 0.f, b3 = 0.f;
    #pragma unroll
    for (int j = 0; j < 4; j++) {
        int ch = l16 * 4 + j;
        float tk = (j == 0) ? tv.x : (j == 1) ? tv.y : (j == 2) ? tv.z : tv.w;
        float rr = fmaxf(tk, 0.f);   // self loop: ea = 0
        a0 += rr * wr2[j][0]; a1 += rr * wr2[j][1];
        a2 += rr * wr2[j][2]; a3 += rr * wr2[j][3];
        float hk = (j == 0) ? hv.x : (j == 1) ? hv.y : (j == 2) ? hv.z : hv.w;
        b0 += hk * s_sw[ch][0]; b1 += hk * s_sw[ch][1];
        b2 += hk * s_sw[ch][2]; b3 += hk * s_sw[ch][3];
    }
    int beg = (int)offsC[c], end = (int)offsC[c + 1];
    const float4 z4 = make_float4(0.f, 0.f, 0.f, 0.f);
    // steady state: er0/er1 + tv0/tv1 (current pair), ern0/ern1 (next records)
    int p = beg;
    float4 er0 = (p     < end) ? colEA[p]     : z4;
    float4 er1 = (p + 1 < end) ? colEA[p + 1] : z4;
    float4 tv0 = (p     < end) ? t4g[__float_as_int(er0.z) * 16 + l16] : z4;
    float4 tv1 = (p + 1 < end) ? t4g[__float_as_int(er1.z) * 16 + l16] : z4;
    float4 ern0 = (p + 2 < end) ? colEA[p + 2] : z4;
    float4 ern1 = (p + 3 < end) ? colEA[p + 3] : z4;
    while (p < end) {
        float4 tvn0 = (p + 2 < end) ? t4g[__float_as_int(ern0.z) * 16 + l16] : z4;
        float4 tvn1 = (p + 3 < end) ? t4g[__float_as_int(ern1.z) * 16 + l16] : z4;
        float4 ernn0 = (p + 4 < end) ? colEA[p + 4] : z4;
        float4 ernn1 = (p + 5 < end) ? colEA[p + 5] : z4;
        {
            float ex = er0.x, ey = er0.y;
            #pragma unroll
            for (int j = 0; j < 4; j++) {
                float tk = (j == 0) ? tv0.x : (j == 1) ? tv0.y : (j == 2) ? tv0.z : tv0.w;
                float pre = tk + ex * w1a[j] + ey * w1b[j];
                float rr = fmaxf(pre, 0.f);
                a0 += rr * wr2[j][0]; a1 += rr * wr2[j][1];
                a2 += rr * wr2[j][2]; a3 += rr * wr2[j][3];
            }
        }
        {
            float ex = er1.x, ey = er1.y;
            #pragma unroll
            for (int j = 0; j < 4; j++) {
                float tk = (j == 0) ? tv1.x : (j == 1) ? tv1.y : (j == 2) ? tv1.z : tv1.w;
                float pre = tk + ex * w1a[j] + ey * w1b[j];
                float rr = fmaxf(pre, 0.f);
                a0 += rr * wr2[j][0]; a1 += rr * wr2[j][1];
                a2 += rr * wr2[j][2]; a3 += rr * wr2[j][3];
            }
        }
        er0 = ern0; er1 = ern1; tv0 = tvn0; tv1 = tvn1;
        ern0 = ernn0; ern1 = ernn1;
        p += 2;
    }
    a0 = dpp_sum16(a0); a1 = dpp_sum16(a1); a2 = dpp_sum16(a2); a3 = dpp_sum16(a3);
    b0 = dpp_sum16(b0); b1 = dpp_sum16(b1); b2 = dpp_sum16(b2); b3 = dpp_sum16(b3);
    if (l16 == 0) {
        float idg = 1.f / deg[c];
        x4b[c] = make_float4(a0 * idg + b0 + rb2[0] + sb[0],
                             a1 * idg + b1 + rb2[1] + sb[1],
                             a2 * idg + b2 + rb2[2] + sb[2],
                             a3 * idg + b3 + rb2[3] + sb[3]);
    }
}

// attention gather, rank-4-factored V; WAVE per dst, 2-deep pipelined slot loop.
// (round-1 form — known good)
__global__ void k5_att(const unsigned* __restrict__ offsC, const float4* __restrict__ colEA,
                       const float4* __restrict__ x4b, const float* __restrict__ cst,
                       const float* __restrict__ cstV, float* __restrict__ att16,
                       float* __restrict__ zbuf) {
    int tid = threadIdx.x;
    int lane = tid & 63;
    int sub = lane >> 4, d = lane & 15, h = d >> 2, a = d & 3;
    const float* C = cst + h * 32;
    int c = (blockIdx.x * blockDim.x + tid) >> 6;   // wave per dst
    if (c >= N_NODES) return;
    float4 xc = x4b[c];
    float g0 = xc.x * C[0]  + xc.y * C[1]  + xc.z * C[2]  + xc.w * C[3]  + C[16];
    float g1 = xc.x * C[4]  + xc.y * C[5]  + xc.z * C[6]  + xc.w * C[7]  + C[17];
    float g2 = xc.x * C[8]  + xc.y * C[9]  + xc.z * C[10] + xc.w * C[11] + C[18];
    float g3 = xc.x * C[12] + xc.y * C[13] + xc.z * C[14] + xc.w * C[15] + C[19];
    float base = C[20] * xc.x + C[21] * xc.y + C[22] * xc.z + C[23] * xc.w + C[24];
    int beg = offsC[c], end = offsC[c + 1];
    float S = 0.f, z = 0.f;
    int p = beg + sub;
    bool vld0 = p < end;
    float4 xr = make_float4(0.f, 0.f, 0.f, 0.f);
    if (vld0) xr = x4b[__float_as_int(colEA[p].z)];
    int pn = p + 4;
    bool vld1 = pn < end;
    int rn = vld1 ? __float_as_int(colEA[pn].z) : 0;
    while (vld0) {
        float4 xrn = make_float4(0.f, 0.f, 0.f, 0.f);
        if (vld1) xrn = x4b[rn];
        int pnn = pn + 4;
        bool vld2 = pnn < end;
        int rnn = vld2 ? __float_as_int(colEA[pnn].z) : 0;
        float s = xr.x * g0 + xr.y * g1 + xr.z * g2 + xr.w * g3 + base;
        float ex = __expf(s);
        float xa = (a == 0) ? xr.x : (a == 1) ? xr.y : (a == 2) ? xr.z : xr.w;
        S += ex * xa;
        z += ex;
        xr = xrn; rn = rnn; vld0 = vld1; vld1 = vld2; pn = pnn;
    }
    S += __shfl_xor(S, 16); S += __shfl_xor(S, 32);
    z += __shfl_xor(z, 16); z += __shfl_xor(z, 32);
    const float* V = cstV + h * 32;
    float c0 = S * V[a * 4 + 0], c1 = S * V[a * 4 + 1];
    float c2 = S * V[a * 4 + 2], c3 = S * V[a * 4 + 3];
    c0 = dpp_addf<DPP_QX1>(c0); c1 = dpp_addf<DPP_QX1>(c1);
    c2 = dpp_addf<DPP_QX1>(c2); c3 = dpp_addf<DPP_QX1>(c3);
    c0 = dpp_addf<DPP_QX2>(c0); c1 = dpp_addf<DPP_QX2>(c1);
    c2 = dpp_addf<DPP_QX2>(c2); c3 = dpp_addf<DPP_QX2>(c3);
    float my = (a == 0) ? c0 : (a == 1) ? c1 : (a == 2) ? c2 : c3;
    if (sub == 0) {
        att16[c * 16 + d] = my + z * V[16 + a];
        if (a == 0) zbuf[c * 4 + h] = z;
    }
}

// reduce zbuf (N_NODES x 4) -> sumexp[4]; LDS block reduction, 49 atomics per head
__global__ void __launch_bounds__(1024) k_zred(const float4* __restrict__ zbuf,
                                               float* __restrict__ sumexp) {
    __shared__ float s[16][4];
    int tid = threadIdx.x;
    int i = blockIdx.x * 1024 + tid;
    float4 v = make_float4(0.f, 0.f, 0.f, 0.f);
    if (i < N_NODES) v = zbuf[i];
    bsum4(v.x, v.y, v.z, v.w);
    int w = tid >> 6;
    if ((tid & 63) == 0) { s[w][0] = v.x; s[w][1] = v.y; s[w][2] = v.z; s[w][3] = v.w; }
    __syncthreads();
    if (tid < 4) {
        float acc = 0.f;
        #pragma unroll
        for (int ww = 0; ww < 16; ww++) acc += s[ww][tid];
        atomicAdd(&sumexp[tid], acc);
    }
}

// final: finalize layer 3 then MLP head (readlane GEMM)
__global__ void k6pred(const float* __restrict__ att16, const float* __restrict__ sumexp,
                       const float4* __restrict__ x4b, const float* __restrict__ ob,
                       const float* __restrict__ g, const float* __restrict__ bb,
                       const float* __restrict__ resw, const float4* __restrict__ xcur,
                       const float* __restrict__ in_w, const float* __restrict__ in_b,
                       const float* __restrict__ w1, const float* __restrict__ b1,
                       const float* __restrict__ w2, const float* __restrict__ b2,
                       float* __restrict__ out) {
    int tid = threadIdx.x;
    int node = (blockIdx.x * blockDim.x + tid) >> 6;
    int lane = tid & 63;
    if (node >= N_NODES) return;
    float z = sumexp[(lane & 15) >> 2];
    float a = 0.f;
    if (lane < 16) a = att16[node * 16 + lane] / z;
    a = dpp_addf<DPP_ROR4>(a);
    a = dpp_addf<DPP_ROR8>(a);
    float y0 = rdlane(a, 0), y1 = rdlane(a, 1), y2 = rdlane(a, 2), y3 = rdlane(a, 3);
    float4 x4v = x4b[node];
    y0 += ob[0] + x4v.x; y1 += ob[1] + x4v.y;
    y2 += ob[2] + x4v.z; y3 += ob[3] + x4v.w;
    float mu = 0.25f * (y0 + y1 + y2 + y3);
    float d0 = y0 - mu, d1 = y1 - mu, d2 = y2 - mu, d3 = y3 - mu;
    float var = 0.25f * (d0 * d0 + d1 * d1 + d2 * d2 + d3 * d3);
    float rs = rsqrtf(var + 1e-5f);
    float4 xold = xcur[node];
    float rw = resw[0];
    float n0 = d0 * rs * g[0] + bb[0] + xold.x * rw;
    float n1 = d1 * rs * g[1] + bb[1] + xold.y * rw;
    float n2 = d2 * rs * g[2] + bb[2] + xold.z * rw;
    float n3 = d3 * rs * g[3] + bb[3] + xold.w * rw;
    float hv = in_b[lane] + n0 * in_w[lane] + n1 * in_w[64 + lane]
             + n2 * in_w[128 + lane] + n3 * in_w[192 + lane];
    int j2 = lane & 31;
    float m = b1[j2];
    for (int k = 0; k < 64; k++) m += rdlane(hv, k) * w1[k * 32 + j2];
    m = fmaxf(m, 0.f);
    float4 w2v = ((const float4*)w2)[j2];
    float v0 = m * w2v.x, v1 = m * w2v.y, v2 = m * w2v.z, v3 = m * w2v.w;
    bsum4(v0, v1, v2, v3);  // each j2 counted twice (both halves) -> *0.5
    float o0 = tanhf(0.5f * v0 + b2[0]) * 0.3f;
    float o1 = tanhf(0.5f * v1 + b2[1]) * 0.3f;
    float o2 = tanhf(0.5f * v2 + b2[2]) * 0.3f;
    float o3 = tanhf(0.5f * v3 + b2[3]) * 0.3f;
    if (lane == 0) ((float4*)out)[node] = make_float4(o0, o1, o2, o3);
}

// ---------- launch ----------
extern "C" void kernel_launch(void* const* d_in, const int* in_sizes, int n_in,
                              void* d_out, int out_size, void* d_ws, size_t ws_size,
                              hipStream_t stream) {
    const float* x        = (const float*)d_in[0];
    const int*   ei       = (const int*)d_in[1];
    const float* ea       = (const float*)d_in[2];
    const float* in_w     = (const float*)d_in[3];
    const float* in_b     = (const float*)d_in[4];
    const float* conv_rw1 = (const float*)d_in[5];
    const float* conv_rb1 = (const float*)d_in[6];
    const float* conv_rw2 = (const float*)d_in[7];
    const float* conv_rb2 = (const float*)d_in[8];
    // d_in[9..12] (imag path) dead: x4 = h4[:, :4] only touches real[:, :4]
    const float* conv_sw  = (const float*)d_in[13];
    const float* conv_sb  = (const float*)d_in[14];
    const float* att_qw   = (const float*)d_in[15];
    const float* att_qb   = (const float*)d_in[16];
    const float* att_kw   = (const float*)d_in[17];
    const float* att_kb   = (const float*)d_in[18];
    const float* att_vw   = (const float*)d_in[19];
    const float* att_vb   = (const float*)d_in[20];
    const float* att_ow   = (const float*)d_in[21];
    const float* att_ob   = (const float*)d_in[22];
    const float* ln_g     = (const float*)d_in[23];
    const float* ln_b     = (const float*)d_in[24];
    const float* out_w1   = (const float*)d_in[25];
    const float* out_b1   = (const float*)d_in[26];
    const float* out_w2   = (const float*)d_in[27];
    const float* out_b2   = (const float*)d_in[28];
    const float* res_w    = (const float*)d_in[29];

    const int* row = ei;
    const int* col = ei + N_EDGES;

    char* ws = (char*)d_ws;
    size_t off = 0;
    auto alloc = [&](size_t bytes) -> void* {
        void* p = ws + off;
        off = (off + bytes + 255) & ~(size_t)255;
        return p;
    };
    float*    deg      = (float*)alloc(N_NODES * 4);
    unsigned* cntC     = (unsigned*)alloc(N_NODES * 4);
    unsigned* offsC    = (unsigned*)alloc((N_NODES + 1) * 4);
    unsigned* bs1      = (unsigned*)alloc(SCAN_NB * 4);
    unsigned* carry1   = (unsigned*)alloc(SCAN_NB * 4);
    unsigned* rankC    = (unsigned*)alloc((size_t)N_EDGES * 4);
    float4*   colEA    = (float4*)alloc((size_t)N_EDGES * 16);
    float*    tbuf     = (float*)alloc((size_t)N_NODES * 64 * 4);
    float*    hb       = (float*)alloc((size_t)N_NODES * 64 * 4);
    float*    att16    = (float*)alloc((size_t)N_NODES * 16 * 4);
    float*    zbuf     = (float*)alloc((size_t)N_NODES * 4 * 4);
    float4*   x4b      = (float4*)alloc((size_t)N_NODES * 16);
    float4*   xcur     = (float4*)alloc((size_t)N_NODES * 16);
    float*    cst      = (float*)alloc(4 * 128 * 4);
    float*    cstV     = (float*)alloc(4 * 128 * 4);
    float*    sumexp   = (float*)alloc(256);

    dim3 b256(256);
    int nodeBlocks  = (N_NODES + 3) / 4;        // wave per node
    int nodeBlocks4 = (N_NODES + 15) / 16;      // wave per 4 nodes
    int edgeTB      = (N_EDGES + 255) / 256;    // thread per edge
    int dstBlocks   = (N_NODES + 15) / 16;      // quarter-wave per dst
    int zredBlocks  = (N_NODES + 1023) / 1024;

    k_h01<<<nodeBlocks4, b256, 0, stream>>>(x, in_w, in_b, conv_rw1, conv_rb1,
                                            hb, xcur, cntC, tbuf);
    k_count<<<edgeTB, b256, 0, stream>>>(col, cntC, rankC);
    k_scanA<<<SCAN_NB, 1024, 0, stream>>>(cntC, offsC, deg, bs1);
    k_scanB<<<1, 64, 0, stream>>>(bs1, carry1, offsC);
    k_scanC<<<SCAN_NB, 1024, 0, stream>>>(offsC, carry1);
    k_write<<<edgeTB, b256, 0, stream>>>(row, col, ea, offsC, rankC, colEA);
    k_prep2<<<8, 64, 0, stream>>>(att_qw, att_qb, att_kw, att_kb,
                                  att_vw, att_vb, att_ow, cst, cstV);

    for (int i = 0; i < 4; i++) {
        const float* rw1 = conv_rw1 + i * 66 * 64;
        const float* rb1 = conv_rb1 + i * 64;
        const float* rw2 = conv_rw2 + i * 64 * 64;
        const float* rb2 = conv_rb2 + i * 64;
        const float* swl = conv_sw + i * 64 * 256;
        const float* sbl = conv_sb + i * 256;

        if (i > 0) {
            k61<<<nodeBlocks4, b256, 0, stream>>>(att16, sumexp, x4b,
                                                  att_ob + (i - 1) * 4, ln_g + (i - 1) * 4,
                                                  ln_b + (i - 1) * 4, res_w + (i - 1),
                                                  in_w, in_b, xcur,
                                                  rw1, rb1, tbuf, hb);
        }
        k23b<<<dstBlocks, b256, 0, stream>>>(offsC, colEA, tbuf, hb,
                                             rw1, rw2, swl, rb2, sbl, deg, x4b, sumexp);
        k5_att<<<nodeBlocks, b256, 0, stream>>>(offsC, colEA, x4b, cst + i * 128,
                                                cstV + i * 128, att16, zbuf);
        k_zred<<<zredBlocks, 1024, 0, stream>>>((const float4*)zbuf, sumexp);
    }
    k6pred<<<nodeBlocks, b256, 0, stream>>>(att16, sumexp, x4b, att_ob + 12, ln_g + 12,
                                            ln_b + 12, res_w + 3, xcur, in_w, in_b,
                                            out_w1, out_b1, out_w2, out_b2, (float*)d_out);
}

// Round 4
// 573.544 us; speedup vs baseline: 1.2913x; 1.0809x over previous
//
#include <hip/hip_runtime.h>
#include <hip/hip_bf16.h>
#include <hip/hip_fp16.h>

#define N_NODES 50000
#define N_EDGES 800000
#define BUCKET 64   // per-dst edge capacity; deg ~ Poisson(16), P(>64) ~ 1e-18

// ---------- helpers ----------
__device__ __forceinline__ float rdlane(float v, int k) {
    return __uint_as_float(__builtin_amdgcn_readlane(__float_as_uint(v), k));
}
template <int CTRL>
__device__ __forceinline__ float dpp_addf(float v) {
    int x = __builtin_amdgcn_update_dpp(0, __float_as_int(v), CTRL, 0xF, 0xF, true);
    return v + __int_as_float(x);
}
#define DPP_QX1  0xB1   // quad_perm [1,0,3,2]
#define DPP_QX2  0x4E   // quad_perm [2,3,0,1]
#define DPP_HM   0x141  // row_half_mirror
#define DPP_RM   0x140  // row_mirror
#define DPP_ROR4 0x124  // row_ror:4
#define DPP_ROR8 0x128  // row_ror:8
__device__ __forceinline__ float dpp_sum16(float v) {
    v = dpp_addf<DPP_QX1>(v);
    v = dpp_addf<DPP_QX2>(v);
    v = dpp_addf<DPP_HM>(v);
    v = dpp_addf<DPP_RM>(v);
    return v;
}
__device__ __forceinline__ void bsum4(float& v0, float& v1, float& v2, float& v3) {
    #pragma unroll
    for (int m = 1; m < 64; m <<= 1) {
        v0 += __shfl_xor(v0, m);
        v1 += __shfl_xor(v1, m);
        v2 += __shfl_xor(v2, m);
        v3 += __shfl_xor(v3, m);
    }
}
// convert 4 packed halves (loaded as float2) to 4 floats
__device__ __forceinline__ void cvt_t4(float2 raw, float tk[4]) {
    __half2 a = ((const __half2*)&raw)[0];
    __half2 b = ((const __half2*)&raw)[1];
    float2 fa = __half22float2(a), fb = __half22float2(b);
    tk[0] = fa.x; tk[1] = fa.y; tk[2] = fb.x; tk[3] = fb.y;
}

// ---------- setup ----------
// fused: h = x@in_w+in_b ; xcur=x ; cntC=0 ; layer-0 t = h@rw1[:64]+rb1 (readlane GEMM)
// t stored fp16 (halves the random-gather bytes in k23b)
__global__ void k_h01(const float* __restrict__ x, const float* __restrict__ in_w,
                      const float* __restrict__ in_b, const float* __restrict__ rw1,
                      const float* __restrict__ rb1, float* __restrict__ hb,
                      float4* __restrict__ xcur, unsigned* __restrict__ cntC,
                      __half* __restrict__ t) {
    int tid = threadIdx.x;
    int wid = (blockIdx.x * blockDim.x + tid) >> 6;
    int lane = tid & 63;
    int n0 = wid * 4;
    if (n0 >= N_NODES) return;
    float iw0 = in_w[lane], iw1 = in_w[64 + lane], iw2 = in_w[128 + lane], iw3 = in_w[192 + lane];
    float ibl = in_b[lane];
    float hv[4];
    #pragma unroll
    for (int i = 0; i < 4; i++) {
        int n = n0 + i;
        hv[i] = 0.f;
        if (n < N_NODES) {
            float4 xv = ((const float4*)x)[n];
            hv[i] = ibl + xv.x * iw0 + xv.y * iw1 + xv.z * iw2 + xv.w * iw3;
            hb[n * 64 + lane] = hv[i];
            if (lane == 0) { xcur[n] = xv; cntC[n] = 0u; }
        }
    }
    float acc[4];
    #pragma unroll
    for (int i = 0; i < 4; i++) acc[i] = rb1[lane];
    for (int k = 0; k < 64; k++) {
        float w = rw1[k * 64 + lane];
        #pragma unroll
        for (int i = 0; i < 4; i++) acc[i] += rdlane(hv[i], k) * w;
    }
    #pragma unroll
    for (int i = 0; i < 4; i++) {
        int n = n0 + i;
        if (n < N_NODES) t[n * 64 + lane] = __float2half(acc[i]);
    }
}

// fused CSR build: slot via returning atomic, record scattered to fixed bucket.
// replaces k_count + 3 scan kernels + k_write.
__global__ void k_cw(const int* __restrict__ row, const int* __restrict__ col,
                     const float* __restrict__ ea, unsigned* __restrict__ cntC,
                     float4* __restrict__ colEA) {
    int e = blockIdx.x * blockDim.x + threadIdx.x;
    if (e >= N_EDGES) return;
    int c = col[e];
    unsigned slot = atomicAdd(&cntC[c], 1u);
    float2 e2 = ((const float2*)ea)[e];
    colEA[(size_t)c * BUCKET + slot] = make_float4(e2.x, e2.y, __int_as_float(row[e]), 0.f);
}

// merged per-layer constants: blocks 0-3 score (M,u,v,w), blocks 4-7 value (Wp,bp)
__global__ void k_prep2(const float* __restrict__ qw, const float* __restrict__ qb,
                        const float* __restrict__ kw, const float* __restrict__ kb,
                        const float* __restrict__ vw, const float* __restrict__ vb,
                        const float* __restrict__ ow, float* __restrict__ cst,
                        float* __restrict__ cstV) {
    int m = threadIdx.x;
    int d = m & 15;
    if (blockIdx.x < 4) {
        int L = blockIdx.x;
        const float* qwl = qw + L * 256; const float* kwl = kw + L * 256;
        const float* qbl = qb + L * 64;  const float* kbl = kb + L * 64;
        float qa[4], ka[4];
        #pragma unroll
        for (int a = 0; a < 4; a++) { qa[a] = qwl[a * 64 + m]; ka[a] = kwl[a * 64 + m]; }
        float qbm = qbl[m], kbm = kbl[m];
        float vals[25];
        int idx = 0;
        #pragma unroll
        for (int a = 0; a < 4; a++)
            #pragma unroll
            for (int b = 0; b < 4; b++) vals[idx++] = qa[a] * ka[b];
        #pragma unroll
        for (int a = 0; a < 4; a++) vals[idx++] = qa[a] * kbm;
        #pragma unroll
        for (int b = 0; b < 4; b++) vals[idx++] = qbm * ka[b];
        vals[24] = qbm * kbm;
        #pragma unroll
        for (int i = 0; i < 25; i++) {
            float v = vals[i];
            v += __shfl_xor(v, 1); v += __shfl_xor(v, 2);
            v += __shfl_xor(v, 4); v += __shfl_xor(v, 8);
            vals[i] = v;
        }
        if (d == 0) {
            float* out = cst + L * 128 + (m >> 4) * 32;
            #pragma unroll
            for (int i = 0; i < 25; i++) out[i] = vals[i] * 0.25f;
        }
    } else {
        int L = blockIdx.x - 4;
        int h = m >> 4;
        const float* vwl = vw + L * 256;
        const float* vbl = vb + L * 64;
        float4 owv = ((const float4*)(ow + L * 256))[m];
        float vals[20];
        #pragma unroll
        for (int a = 0; a < 4; a++) {
            float v = vwl[a * 64 + m];
            vals[a * 4 + 0] = v * owv.x; vals[a * 4 + 1] = v * owv.y;
            vals[a * 4 + 2] = v * owv.z; vals[a * 4 + 3] = v * owv.w;
        }
        float b = vbl[m];
        vals[16] = b * owv.x; vals[17] = b * owv.y; vals[18] = b * owv.z; vals[19] = b * owv.w;
        #pragma unroll
        for (int i = 0; i < 20; i++) {
            float v = vals[i];
            v += __shfl_xor(v, 1); v += __shfl_xor(v, 2);
            v += __shfl_xor(v, 4); v += __shfl_xor(v, 8);
            vals[i] = v;
        }
        if (d == 0) {
            float* out = cstV + L * 128 + h * 32;
            #pragma unroll
            for (int i = 0; i < 20; i++) out[i] = vals[i];
        }
    }
}

// ---------- per-layer ----------
// layers 1..3: finalize prev layer, write h, compute this layer's t (readlane GEMM)
__global__ void k61(const float* __restrict__ att16, const float* __restrict__ sumexp,
                    const float4* __restrict__ x4b, const float* __restrict__ ob,
                    const float* __restrict__ g, const float* __restrict__ bb,
                    const float* __restrict__ resw, const float* __restrict__ in_w,
                    const float* __restrict__ in_b, float4* __restrict__ xcur,
                    const float* __restrict__ rw1, const float* __restrict__ rb1,
                    __half* __restrict__ t, float* __restrict__ hb) {
    int tid = threadIdx.x;
    int wid = (blockIdx.x * blockDim.x + tid) >> 6;
    int lane = tid & 63;
    int n0 = wid * 4;
    if (n0 >= N_NODES) return;
    float iw0 = in_w[lane], iw1 = in_w[64 + lane], iw2 = in_w[128 + lane], iw3 = in_w[192 + lane];
    float ibl = in_b[lane];
    float z = sumexp[(lane & 15) >> 2];
    float ob0 = ob[0], ob1 = ob[1], ob2 = ob[2], ob3 = ob[3];
    float g0 = g[0], g1 = g[1], g2 = g[2], g3 = g[3];
    float bb0 = bb[0], bb1 = bb[1], bb2 = bb[2], bb3 = bb[3];
    float rw = resw[0];
    float hv[4];
    #pragma unroll
    for (int i = 0; i < 4; i++) {
        int n = n0 + i;
        float a = 0.f;
        if (n < N_NODES && lane < 16) a = att16[n * 16 + lane] / z;
        a = dpp_addf<DPP_ROR4>(a);
        a = dpp_addf<DPP_ROR8>(a);
        float y0 = rdlane(a, 0), y1 = rdlane(a, 1), y2 = rdlane(a, 2), y3 = rdlane(a, 3);
        hv[i] = 0.f;
        if (n < N_NODES) {
            float4 x4v = x4b[n];
            y0 += ob0 + x4v.x; y1 += ob1 + x4v.y;
            y2 += ob2 + x4v.z; y3 += ob3 + x4v.w;
            float mu = 0.25f * (y0 + y1 + y2 + y3);
            float d0 = y0 - mu, d1 = y1 - mu, d2 = y2 - mu, d3 = y3 - mu;
            float var = 0.25f * (d0 * d0 + d1 * d1 + d2 * d2 + d3 * d3);
            float rs = rsqrtf(var + 1e-5f);
            float4 xold = xcur[n];
            float nn0 = d0 * rs * g0 + bb0 + xold.x * rw;
            float nn1 = d1 * rs * g1 + bb1 + xold.y * rw;
            float nn2 = d2 * rs * g2 + bb2 + xold.z * rw;
            float nn3 = d3 * rs * g3 + bb3 + xold.w * rw;
            if (lane == 0) xcur[n] = make_float4(nn0, nn1, nn2, nn3);
            hv[i] = ibl + nn0 * iw0 + nn1 * iw1 + nn2 * iw2 + nn3 * iw3;
            hb[n * 64 + lane] = hv[i];
        }
    }
    float acc[4];
    #pragma unroll
    for (int i = 0; i < 4; i++) acc[i] = rb1[lane];
    for (int k = 0; k < 64; k++) {
        float w = rw1[k * 64 + lane];
        #pragma unroll
        for (int i = 0; i < 4; i++) acc[i] += rdlane(hv[i], k) * w;
    }
    #pragma unroll
    for (int i = 0; i < 4; i++) {
        int n = n0 + i;
        if (n < N_NODES) t[n * 64 + lane] = __float2half(acc[i]);
    }
}

// fused msg-compute + gather + self-loop + base + x4: quarter-wave per dst.
// t is fp16 (8B per lane per row) -> halves the miss-queue-limited random fetch.
// round-1 loop shape (1-ahead t, 2-ahead records), no launch_bounds (no spill).
__global__ void k23b(const unsigned* __restrict__ cntC, const float4* __restrict__ colEA,
                     const __half* __restrict__ t, const float* __restrict__ hb,
                     const float* __restrict__ rw1, const float* __restrict__ rw2,
                     const float* __restrict__ sw, const float* __restrict__ rb2,
                     const float* __restrict__ sb,
                     float4* __restrict__ x4b, float* __restrict__ sumexp) {
    __shared__ float s_rw2[64][4];
    __shared__ float s_sw[64][4];
    __shared__ float s_w1[128];
    int tid = threadIdx.x;
    { int r = tid >> 2, cc = tid & 3; s_rw2[r][cc] = rw2[r * 64 + cc]; s_sw[r][cc] = sw[r * 256 + cc]; }
    if (tid < 128) s_w1[tid] = rw1[64 * 64 + tid];
    if (blockIdx.x == 0 && tid < 4) sumexp[tid] = 0.f;
    __syncthreads();
    int lane = tid & 63;
    int sub = lane >> 4, l16 = lane & 15;
    int gid = (blockIdx.x * blockDim.x + tid) >> 6;
    int c = gid * 4 + sub;
    if (c >= N_NODES) return;
    // per-lane weights for fixed channels ch = l16*4 + j
    float w1a[4], w1b[4], wr2[4][4];
    #pragma unroll
    for (int j = 0; j < 4; j++) {
        int ch = l16 * 4 + j;
        w1a[j] = s_w1[ch];
        w1b[j] = s_w1[64 + ch];
        #pragma unroll
        for (int o = 0; o < 4; o++) wr2[j][o] = s_rw2[ch][o];
    }
    float2 trS = *(const float2*)(t + (size_t)c * 64 + l16 * 4);
    float4 hv = ((const float4*)hb)[c * 16 + l16];
    float a0 = 0.f, a1 = 0.f, a2 = 0.f, a3 = 0.f;
    float b0 = 0.f, b1 = 0.f, b2 = 0.f, b3 = 0.f;
    {
        float tk[4];
        cvt_t4(trS, tk);
        #pragma unroll
        for (int j = 0; j < 4; j++) {
            int ch = l16 * 4 + j;
            float rr = fmaxf(tk[j], 0.f);   // self loop: ea = 0
            a0 += rr * wr2[j][0]; a1 += rr * wr2[j][1];
            a2 += rr * wr2[j][2]; a3 += rr * wr2[j][3];
            float hk = (j == 0) ? hv.x : (j == 1) ? hv.y : (j == 2) ? hv.z : hv.w;
            b0 += hk * s_sw[ch][0]; b1 += hk * s_sw[ch][1];
            b2 += hk * s_sw[ch][2]; b3 += hk * s_sw[ch][3];
        }
    }
    int cnt = (int)cntC[c];
    const float4* rowE = colEA + (size_t)c * BUCKET;
    const float4 z4 = make_float4(0.f, 0.f, 0.f, 0.f);
    const float2 z2 = make_float2(0.f, 0.f);
    int p = 0;
    bool vld0 = p < cnt;
    float4 erA = vld0 ? rowE[0] : z4;
    float2 trA = vld0 ? *(const float2*)(t + (size_t)__float_as_int(erA.z) * 64 + l16 * 4) : z2;
    int pn = 1;
    bool vld1 = pn < cnt;
    float4 erB = vld1 ? rowE[1] : z4;
    while (vld0) {
        float2 trB = vld1 ? *(const float2*)(t + (size_t)__float_as_int(erB.z) * 64 + l16 * 4) : z2;
        int pnn = pn + 1;
        bool vld2 = pnn < cnt;
        float4 erC = vld2 ? rowE[pnn] : z4;
        float tk[4];
        cvt_t4(trA, tk);
        float ex = erA.x, ey = erA.y;
        #pragma unroll
        for (int j = 0; j < 4; j++) {
            float pre = tk[j] + ex * w1a[j] + ey * w1b[j];
            float rr = fmaxf(pre, 0.f);
            a0 += rr * wr2[j][0]; a1 += rr * wr2[j][1];
            a2 += rr * wr2[j][2]; a3 += rr * wr2[j][3];
        }
        erA = erB; trA = trB; erB = erC;
        vld0 = vld1; vld1 = vld2; pn = pnn;
    }
    a0 = dpp_sum16(a0); a1 = dpp_sum16(a1); a2 = dpp_sum16(a2); a3 = dpp_sum16(a3);
    b0 = dpp_sum16(b0); b1 = dpp_sum16(b1); b2 = dpp_sum16(b2); b3 = dpp_sum16(b3);
    if (l16 == 0) {
        float idg = 1.f / (float)(cnt + 1);
        x4b[c] = make_float4(a0 * idg + b0 + rb2[0] + sb[0],
                             a1 * idg + b1 + rb2[1] + sb[1],
                             a2 * idg + b2 + rb2[2] + sb[2],
                             a3 * idg + b3 + rb2[3] + sb[3]);
    }
}

// attention gather, rank-4-factored V; WAVE per dst, 2-deep pipelined slot loop.
__global__ void k5_att(const unsigned* __restrict__ cntC, const float4* __restrict__ colEA,
                       const float4* __restrict__ x4b, const float* __restrict__ cst,
                       const float* __restrict__ cstV, float* __restrict__ att16,
                       float* __restrict__ zbuf) {
    int tid = threadIdx.x;
    int lane = tid & 63;
    int sub = lane >> 4, d = lane & 15, h = d >> 2, a = d & 3;
    const float* C = cst + h * 32;
    int c = (blockIdx.x * blockDim.x + tid) >> 6;   // wave per dst
    if (c >= N_NODES) return;
    float4 xc = x4b[c];
    float g0 = xc.x * C[0]  + xc.y * C[1]  + xc.z * C[2]  + xc.w * C[3]  + C[16];
    float g1 = xc.x * C[4]  + xc.y * C[5]  + xc.z * C[6]  + xc.w * C[7]  + C[17];
    float g2 = xc.x * C[8]  + xc.y * C[9]  + xc.z * C[10] + xc.w * C[11] + C[18];
    float g3 = xc.x * C[12] + xc.y * C[13] + xc.z * C[14] + xc.w * C[15] + C[19];
    float base = C[20] * xc.x + C[21] * xc.y + C[22] * xc.z + C[23] * xc.w + C[24];
    int cnt = (int)cntC[c];
    const float4* rowE = colEA + (size_t)c * BUCKET;
    float S = 0.f, z = 0.f;
    int p = sub;
    bool vld0 = p < cnt;
    float4 xr = make_float4(0.f, 0.f, 0.f, 0.f);
    if (vld0) xr = x4b[__float_as_int(rowE[p].z)];
    int pn = p + 4;
    bool vld1 = pn < cnt;
    int rn = vld1 ? __float_as_int(rowE[pn].z) : 0;
    while (vld0) {
        float4 xrn = make_float4(0.f, 0.f, 0.f, 0.f);
        if (vld1) xrn = x4b[rn];
        int pnn = pn + 4;
        bool vld2 = pnn < cnt;
        int rnn = vld2 ? __float_as_int(rowE[pnn].z) : 0;
        float s = xr.x * g0 + xr.y * g1 + xr.z * g2 + xr.w * g3 + base;
        float ex = __expf(s);
        float xa = (a == 0) ? xr.x : (a == 1) ? xr.y : (a == 2) ? xr.z : xr.w;
        S += ex * xa;
        z += ex;
        xr = xrn; rn = rnn; vld0 = vld1; vld1 = vld2; pn = pnn;
    }
    S += __shfl_xor(S, 16); S += __shfl_xor(S, 32);
    z += __shfl_xor(z, 16); z += __shfl_xor(z, 32);
    const float* V = cstV + h * 32;
    float c0 = S * V[a * 4 + 0], c1 = S * V[a * 4 + 1];
    float c2 = S * V[a * 4 + 2], c3 = S * V[a * 4 + 3];
    c0 = dpp_addf<DPP_QX1>(c0); c1 = dpp_addf<DPP_QX1>(c1);
    c2 = dpp_addf<DPP_QX1>(c2); c3 = dpp_addf<DPP_QX1>(c3);
    c0 = dpp_addf<DPP_QX2>(c0); c1 = dpp_addf<DPP_QX2>(c1);
    c2 = dpp_addf<DPP_QX2>(c2); c3 = dpp_addf<DPP_QX2>(c3);
    float my = (a == 0) ? c0 : (a == 1) ? c1 : (a == 2) ? c2 : c3;
    if (sub == 0) {
        att16[c * 16 + d] = my + z * V[16 + a];
        if (a == 0) zbuf[c * 4 + h] = z;
    }
}

// reduce zbuf (N_NODES x 4) -> sumexp[4]; LDS block reduction, 49 atomics per head
__global__ void __launch_bounds__(1024) k_zred(const float4* __restrict__ zbuf,
                                               float* __restrict__ sumexp) {
    __shared__ float s[16][4];
    int tid = threadIdx.x;
    int i = blockIdx.x * 1024 + tid;
    float4 v = make_float4(0.f, 0.f, 0.f, 0.f);
    if (i < N_NODES) v = zbuf[i];
    bsum4(v.x, v.y, v.z, v.w);
    int w = tid >> 6;
    if ((tid & 63) == 0) { s[w][0] = v.x; s[w][1] = v.y; s[w][2] = v.z; s[w][3] = v.w; }
    __syncthreads();
    if (tid < 4) {
        float acc = 0.f;
        #pragma unroll
        for (int ww = 0; ww < 16; ww++) acc += s[ww][tid];
        atomicAdd(&sumexp[tid], acc);
    }
}

// final: finalize layer 3 then MLP head (readlane GEMM)
__global__ void k6pred(const float* __restrict__ att16, const float* __restrict__ sumexp,
                       const float4* __restrict__ x4b, const float* __restrict__ ob,
                       const float* __restrict__ g, const float* __restrict__ bb,
                       const float* __restrict__ resw, const float4* __restrict__ xcur,
                       const float* __restrict__ in_w, const float* __restrict__ in_b,
                       const float* __restrict__ w1, const float* __restrict__ b1,
                       const float* __restrict__ w2, const float* __restrict__ b2,
                       float* __restrict__ out) {
    int tid = threadIdx.x;
    int node = (blockIdx.x * blockDim.x + tid) >> 6;
    int lane = tid & 63;
    if (node >= N_NODES) return;
    float z = sumexp[(lane & 15) >> 2];
    float a = 0.f;
    if (lane < 16) a = att16[node * 16 + lane] / z;
    a = dpp_addf<DPP_ROR4>(a);
    a = dpp_addf<DPP_ROR8>(a);
    float y0 = rdlane(a, 0), y1 = rdlane(a, 1), y2 = rdlane(a, 2), y3 = rdlane(a, 3);
    float4 x4v = x4b[node];
    y0 += ob[0] + x4v.x; y1 += ob[1] + x4v.y;
    y2 += ob[2] + x4v.z; y3 += ob[3] + x4v.w;
    float mu = 0.25f * (y0 + y1 + y2 + y3);
    float d0 = y0 - mu, d1 = y1 - mu, d2 = y2 - mu, d3 = y3 - mu;
    float var = 0.25f * (d0 * d0 + d1 * d1 + d2 * d2 + d3 * d3);
    float rs = rsqrtf(var + 1e-5f);
    float4 xold = xcur[node];
    float rw = resw[0];
    float n0 = d0 * rs * g[0] + bb[0] + xold.x * rw;
    float n1 = d1 * rs * g[1] + bb[1] + xold.y * rw;
    float n2 = d2 * rs * g[2] + bb[2] + xold.z * rw;
    float n3 = d3 * rs * g[3] + bb[3] + xold.w * rw;
    float hv = in_b[lane] + n0 * in_w[lane] + n1 * in_w[64 + lane]
             + n2 * in_w[128 + lane] + n3 * in_w[192 + lane];
    int j2 = lane & 31;
    float m = b1[j2];
    for (int k = 0; k < 64; k++) m += rdlane(hv, k) * w1[k * 32 + j2];
    m = fmaxf(m, 0.f);
    float4 w2v = ((const float4*)w2)[j2];
    float v0 = m * w2v.x, v1 = m * w2v.y, v2 = m * w2v.z, v3 = m * w2v.w;
    bsum4(v0, v1, v2, v3);  // each j2 counted twice (both halves) -> *0.5
    float o0 = tanhf(0.5f * v0 + b2[0]) * 0.3f;
    float o1 = tanhf(0.5f * v1 + b2[1]) * 0.3f;
    float o2 = tanhf(0.5f * v2 + b2[2]) * 0.3f;
    float o3 = tanhf(0.5f * v3 + b2[3]) * 0.3f;
    if (lane == 0) ((float4*)out)[node] = make_float4(o0, o1, o2, o3);
}

// ---------- launch ----------
extern "C" void kernel_launch(void* const* d_in, const int* in_sizes, int n_in,
                              void* d_out, int out_size, void* d_ws, size_t ws_size,
                              hipStream_t stream) {
    const float* x        = (const float*)d_in[0];
    const int*   ei       = (const int*)d_in[1];
    const float* ea       = (const float*)d_in[2];
    const float* in_w     = (const float*)d_in[3];
    const float* in_b     = (const float*)d_in[4];
    const float* conv_rw1 = (const float*)d_in[5];
    const float* conv_rb1 = (const float*)d_in[6];
    const float* conv_rw2 = (const float*)d_in[7];
    const float* conv_rb2 = (const float*)d_in[8];
    // d_in[9..12] (imag path) dead: x4 = h4[:, :4] only touches real[:, :4]
    const float* conv_sw  = (const float*)d_in[13];
    const float* conv_sb  = (const float*)d_in[14];
    const float* att_qw   = (const float*)d_in[15];
    const float* att_qb   = (const float*)d_in[16];
    const float* att_kw   = (const float*)d_in[17];
    const float* att_kb   = (const float*)d_in[18];
    const float* att_vw   = (const float*)d_in[19];
    const float* att_vb   = (const float*)d_in[20];
    const float* att_ow   = (const float*)d_in[21];
    const float* att_ob   = (const float*)d_in[22];
    const float* ln_g     = (const float*)d_in[23];
    const float* ln_b     = (const float*)d_in[24];
    const float* out_w1   = (const float*)d_in[25];
    const float* out_b1   = (const float*)d_in[26];
    const float* out_w2   = (const float*)d_in[27];
    const float* out_b2   = (const float*)d_in[28];
    const float* res_w    = (const float*)d_in[29];

    const int* row = ei;
    const int* col = ei + N_EDGES;

    char* ws = (char*)d_ws;
    size_t off = 0;
    auto alloc = [&](size_t bytes) -> void* {
        void* p = ws + off;
        off = (off + bytes + 255) & ~(size_t)255;
        return p;
    };
    unsigned* cntC     = (unsigned*)alloc(N_NODES * 4);
    float4*   colEA    = (float4*)alloc((size_t)N_NODES * BUCKET * 16);
    __half*   tbuf     = (__half*)alloc((size_t)N_NODES * 64 * 2);
    float*    hb       = (float*)alloc((size_t)N_NODES * 64 * 4);
    float*    att16    = (float*)alloc((size_t)N_NODES * 16 * 4);
    float*    zbuf     = (float*)alloc((size_t)N_NODES * 4 * 4);
    float4*   x4b      = (float4*)alloc((size_t)N_NODES * 16);
    float4*   xcur     = (float4*)alloc((size_t)N_NODES * 16);
    float*    cst      = (float*)alloc(4 * 128 * 4);
    float*    cstV     = (float*)alloc(4 * 128 * 4);
    float*    sumexp   = (float*)alloc(256);

    dim3 b256(256);
    int nodeBlocks  = (N_NODES + 3) / 4;        // wave per node
    int nodeBlocks4 = (N_NODES + 15) / 16;      // wave per 4 nodes
    int edgeTB      = (N_EDGES + 255) / 256;    // thread per edge
    int dstBlocks   = (N_NODES + 15) / 16;      // quarter-wave per dst
    int zredBlocks  = (N_NODES + 1023) / 1024;

    k_h01<<<nodeBlocks4, b256, 0, stream>>>(x, in_w, in_b, conv_rw1, conv_rb1,
                                            hb, xcur, cntC, tbuf);
    k_cw<<<edgeTB, b256, 0, stream>>>(row, col, ea, cntC, colEA);
    k_prep2<<<8, 64, 0, stream>>>(att_qw, att_qb, att_kw, att_kb,
                                  att_vw, att_vb, att_ow, cst, cstV);

    for (int i = 0; i < 4; i++) {
        const float* rw1 = conv_rw1 + i * 66 * 64;
        const float* rb1 = conv_rb1 + i * 64;
        const float* rw2 = conv_rw2 + i * 64 * 64;
        const float* rb2 = conv_rb2 + i * 64;
        const float* swl = conv_sw + i * 64 * 256;
        const float* sbl = conv_sb + i * 256;

        if (i > 0) {
            k61<<<nodeBlocks4, b256, 0, stream>>>(att16, sumexp, x4b,
                                                  att_ob + (i - 1) * 4, ln_g + (i - 1) * 4,
                                                  ln_b + (i - 1) * 4, res_w + (i - 1),
                                                  in_w, in_b, xcur,
                                                  rw1, rb1, tbuf, hb);
        }
        k23b<<<dstBlocks, b256, 0, stream>>>(cntC, colEA, tbuf, hb,
                                             rw1, rw2, swl, rb2, sbl, x4b, sumexp);
        k5_att<<<nodeBlocks, b256, 0, stream>>>(cntC, colEA, x4b, cst + i * 128,
                                                cstV + i * 128, att16, zbuf);
        k_zred<<<zredBlocks, 1024, 0, stream>>>((const float4*)zbuf, sumexp);
    }
    k6pred<<<nodeBlocks, b256, 0, stream>>>(att16, sumexp, x4b, att_ob + 12, ln_g + 12,
                                            ln_b + 12, res_w + 3, xcur, in_w, in_b,
                                            out_w1, out_b1, out_w2, out_b2, (float*)d_out);
}

// Round 5
// 551.704 us; speedup vs baseline: 1.3424x; 1.0396x over previous
//
#include <hip/hip_runtime.h>
#include <hip/hip_bf16.h>
#include <hip/hip_fp16.h>

#define N_NODES 50000
#define N_EDGES 800000
#define BUCKET 64   // per-dst edge capacity; deg ~ Poisson(16), P(>64) ~ 1e-18
#define EDGE_TB 3125   // (N_EDGES+255)/256
#define NODE_NB 3125   // (N_NODES+15)/16

// ---------- helpers ----------
__device__ __forceinline__ float rdlane(float v, int k) {
    return __uint_as_float(__builtin_amdgcn_readlane(__float_as_uint(v), k));
}
template <int CTRL>
__device__ __forceinline__ float dpp_addf(float v) {
    int x = __builtin_amdgcn_update_dpp(0, __float_as_int(v), CTRL, 0xF, 0xF, true);
    return v + __int_as_float(x);
}
#define DPP_QX1  0xB1   // quad_perm [1,0,3,2]
#define DPP_QX2  0x4E   // quad_perm [2,3,0,1]
#define DPP_HM   0x141  // row_half_mirror
#define DPP_RM   0x140  // row_mirror
#define DPP_ROR4 0x124  // row_ror:4
#define DPP_ROR8 0x128  // row_ror:8
__device__ __forceinline__ float dpp_sum16(float v) {
    v = dpp_addf<DPP_QX1>(v);
    v = dpp_addf<DPP_QX2>(v);
    v = dpp_addf<DPP_HM>(v);
    v = dpp_addf<DPP_RM>(v);
    return v;
}
__device__ __forceinline__ void bsum4(float& v0, float& v1, float& v2, float& v3) {
    #pragma unroll
    for (int m = 1; m < 64; m <<= 1) {
        v0 += __shfl_xor(v0, m);
        v1 += __shfl_xor(v1, m);
        v2 += __shfl_xor(v2, m);
        v3 += __shfl_xor(v3, m);
    }
}
// convert 4 packed halves (loaded as float2) to 4 floats
__device__ __forceinline__ void cvt_t4(float2 raw, float tk[4]) {
    __half2 a = ((const __half2*)&raw)[0];
    __half2 b = ((const __half2*)&raw)[1];
    float2 fa = __half22float2(a), fb = __half22float2(b);
    tk[0] = fa.x; tk[1] = fa.y; tk[2] = fb.x; tk[3] = fb.y;
}

// ---------- fused setup ----------
// grid: [0, EDGE_TB) edge scatter (latency-bound, idle VALU)
//       [EDGE_TB, EDGE_TB+NODE_NB) node init: h, xcur, layer-0 t (VALU-bound)
//       [EDGE_TB+NODE_NB, +8) attention constant prep
// The node/prep work fills the scatter's dead cycles. cntC zeroed by memset.
__global__ void k_setup(const float* __restrict__ x, const float* __restrict__ in_w,
                        const float* __restrict__ in_b, const float* __restrict__ rw1,
                        const float* __restrict__ rb1, float* __restrict__ hb,
                        float4* __restrict__ xcur, unsigned* __restrict__ cntC,
                        __half* __restrict__ t,
                        const int* __restrict__ row, const int* __restrict__ col,
                        const float* __restrict__ ea, uint2* __restrict__ colEA,
                        const float* __restrict__ qw, const float* __restrict__ qb,
                        const float* __restrict__ kw, const float* __restrict__ kb,
                        const float* __restrict__ vw, const float* __restrict__ vb,
                        const float* __restrict__ ow, float* __restrict__ cst,
                        float* __restrict__ cstV) {
    int tid = threadIdx.x;
    if (blockIdx.x < EDGE_TB) {
        // ---- edge scatter: 8B record {half2 ea, src} ----
        int e = blockIdx.x * 256 + tid;
        if (e < N_EDGES) {
            int c = col[e];
            unsigned slot = atomicAdd(&cntC[c], 1u);
            float2 e2 = ((const float2*)ea)[e];
            __half2 h2 = __floats2half2_rn(e2.x, e2.y);
            colEA[(size_t)c * BUCKET + slot] =
                make_uint2(*reinterpret_cast<unsigned*>(&h2), (unsigned)row[e]);
        }
        return;
    }
    if (blockIdx.x < EDGE_TB + NODE_NB) {
        // ---- node init (old k_h01, minus cntC zeroing) ----
        int wid = ((blockIdx.x - EDGE_TB) * 256 + tid) >> 6;
        int lane = tid & 63;
        int n0 = wid * 4;
        if (n0 >= N_NODES) return;
        float iw0 = in_w[lane], iw1 = in_w[64 + lane], iw2 = in_w[128 + lane], iw3 = in_w[192 + lane];
        float ibl = in_b[lane];
        float hv[4];
        #pragma unroll
        for (int i = 0; i < 4; i++) {
            int n = n0 + i;
            hv[i] = 0.f;
            if (n < N_NODES) {
                float4 xv = ((const float4*)x)[n];
                hv[i] = ibl + xv.x * iw0 + xv.y * iw1 + xv.z * iw2 + xv.w * iw3;
                hb[n * 64 + lane] = hv[i];
                if (lane == 0) xcur[n] = xv;
            }
        }
        float acc[4];
        #pragma unroll
        for (int i = 0; i < 4; i++) acc[i] = rb1[lane];
        for (int k = 0; k < 64; k++) {
            float w = rw1[k * 64 + lane];
            #pragma unroll
            for (int i = 0; i < 4; i++) acc[i] += rdlane(hv[i], k) * w;
        }
        #pragma unroll
        for (int i = 0; i < 4; i++) {
            int n = n0 + i;
            if (n < N_NODES) t[n * 64 + lane] = __float2half(acc[i]);
        }
        return;
    }
    // ---- attention constant prep (old k_prep2; 8 logical blocks, 64 threads) ----
    int pb = blockIdx.x - (EDGE_TB + NODE_NB);
    int m = tid;
    if (m >= 64) return;
    int d = m & 15;
    if (pb < 4) {
        int L = pb;
        const float* qwl = qw + L * 256; const float* kwl = kw + L * 256;
        const float* qbl = qb + L * 64;  const float* kbl = kb + L * 64;
        float qa[4], ka[4];
        #pragma unroll
        for (int a = 0; a < 4; a++) { qa[a] = qwl[a * 64 + m]; ka[a] = kwl[a * 64 + m]; }
        float qbm = qbl[m], kbm = kbl[m];
        float vals[25];
        int idx = 0;
        #pragma unroll
        for (int a = 0; a < 4; a++)
            #pragma unroll
            for (int b = 0; b < 4; b++) vals[idx++] = qa[a] * ka[b];
        #pragma unroll
        for (int a = 0; a < 4; a++) vals[idx++] = qa[a] * kbm;
        #pragma unroll
        for (int b = 0; b < 4; b++) vals[idx++] = qbm * ka[b];
        vals[24] = qbm * kbm;
        #pragma unroll
        for (int i = 0; i < 25; i++) {
            float v = vals[i];
            v += __shfl_xor(v, 1); v += __shfl_xor(v, 2);
            v += __shfl_xor(v, 4); v += __shfl_xor(v, 8);
            vals[i] = v;
        }
        if (d == 0) {
            float* out = cst + L * 128 + (m >> 4) * 32;
            #pragma unroll
            for (int i = 0; i < 25; i++) out[i] = vals[i] * 0.25f;
        }
    } else {
        int L = pb - 4;
        int h = m >> 4;
        const float* vwl = vw + L * 256;
        const float* vbl = vb + L * 64;
        float4 owv = ((const float4*)(ow + L * 256))[m];
        float vals[20];
        #pragma unroll
        for (int a = 0; a < 4; a++) {
            float v = vwl[a * 64 + m];
            vals[a * 4 + 0] = v * owv.x; vals[a * 4 + 1] = v * owv.y;
            vals[a * 4 + 2] = v * owv.z; vals[a * 4 + 3] = v * owv.w;
        }
        float b = vbl[m];
        vals[16] = b * owv.x; vals[17] = b * owv.y; vals[18] = b * owv.z; vals[19] = b * owv.w;
        #pragma unroll
        for (int i = 0; i < 20; i++) {
            float v = vals[i];
            v += __shfl_xor(v, 1); v += __shfl_xor(v, 2);
            v += __shfl_xor(v, 4); v += __shfl_xor(v, 8);
            vals[i] = v;
        }
        if (d == 0) {
            float* out = cstV + L * 128 + h * 32;
            #pragma unroll
            for (int i = 0; i < 20; i++) out[i] = vals[i];
        }
    }
}

// ---------- per-layer ----------
// layers 1..3: finalize prev layer, write h, compute this layer's t (readlane GEMM)
__global__ void k61(const float* __restrict__ att16, const float* __restrict__ sumexp,
                    const float4* __restrict__ x4b, const float* __restrict__ ob,
                    const float* __restrict__ g, const float* __restrict__ bb,
                    const float* __restrict__ resw, const float* __restrict__ in_w,
                    const float* __restrict__ in_b, float4* __restrict__ xcur,
                    const float* __restrict__ rw1, const float* __restrict__ rb1,
                    __half* __restrict__ t, float* __restrict__ hb) {
    int tid = threadIdx.x;
    int wid = (blockIdx.x * blockDim.x + tid) >> 6;
    int lane = tid & 63;
    int n0 = wid * 4;
    if (n0 >= N_NODES) return;
    float iw0 = in_w[lane], iw1 = in_w[64 + lane], iw2 = in_w[128 + lane], iw3 = in_w[192 + lane];
    float ibl = in_b[lane];
    float z = sumexp[(lane & 15) >> 2];
    float ob0 = ob[0], ob1 = ob[1], ob2 = ob[2], ob3 = ob[3];
    float g0 = g[0], g1 = g[1], g2 = g[2], g3 = g[3];
    float bb0 = bb[0], bb1 = bb[1], bb2 = bb[2], bb3 = bb[3];
    float rw = resw[0];
    float hv[4];
    #pragma unroll
    for (int i = 0; i < 4; i++) {
        int n = n0 + i;
        float a = 0.f;
        if (n < N_NODES && lane < 16) a = att16[n * 16 + lane] / z;
        a = dpp_addf<DPP_ROR4>(a);
        a = dpp_addf<DPP_ROR8>(a);
        float y0 = rdlane(a, 0), y1 = rdlane(a, 1), y2 = rdlane(a, 2), y3 = rdlane(a, 3);
        hv[i] = 0.f;
        if (n < N_NODES) {
            float4 x4v = x4b[n];
            y0 += ob0 + x4v.x; y1 += ob1 + x4v.y;
            y2 += ob2 + x4v.z; y3 += ob3 + x4v.w;
            float mu = 0.25f * (y0 + y1 + y2 + y3);
            float d0 = y0 - mu, d1 = y1 - mu, d2 = y2 - mu, d3 = y3 - mu;
            float var = 0.25f * (d0 * d0 + d1 * d1 + d2 * d2 + d3 * d3);
            float rs = rsqrtf(var + 1e-5f);
            float4 xold = xcur[n];
            float nn0 = d0 * rs * g0 + bb0 + xold.x * rw;
            float nn1 = d1 * rs * g1 + bb1 + xold.y * rw;
            float nn2 = d2 * rs * g2 + bb2 + xold.z * rw;
            float nn3 = d3 * rs * g3 + bb3 + xold.w * rw;
            if (lane == 0) xcur[n] = make_float4(nn0, nn1, nn2, nn3);
            hv[i] = ibl + nn0 * iw0 + nn1 * iw1 + nn2 * iw2 + nn3 * iw3;
            hb[n * 64 + lane] = hv[i];
        }
    }
    float acc[4];
    #pragma unroll
    for (int i = 0; i < 4; i++) acc[i] = rb1[lane];
    for (int k = 0; k < 64; k++) {
        float w = rw1[k * 64 + lane];
        #pragma unroll
        for (int i = 0; i < 4; i++) acc[i] += rdlane(hv[i], k) * w;
    }
    #pragma unroll
    for (int i = 0; i < 4; i++) {
        int n = n0 + i;
        if (n < N_NODES) t[n * 64 + lane] = __float2half(acc[i]);
    }
}

// fused msg-compute + gather + self-loop + base + x4: quarter-wave per dst.
// fp16 t rows (8B/lane), 8B records {half2 ea, src}.
__global__ void k23b(const unsigned* __restrict__ cntC, const uint2* __restrict__ colEA,
                     const __half* __restrict__ t, const float* __restrict__ hb,
                     const float* __restrict__ rw1, const float* __restrict__ rw2,
                     const float* __restrict__ sw, const float* __restrict__ rb2,
                     const float* __restrict__ sb,
                     float4* __restrict__ x4b, float* __restrict__ sumexp) {
    __shared__ float s_rw2[64][4];
    __shared__ float s_sw[64][4];
    __shared__ float s_w1[128];
    int tid = threadIdx.x;
    { int r = tid >> 2, cc = tid & 3; s_rw2[r][cc] = rw2[r * 64 + cc]; s_sw[r][cc] = sw[r * 256 + cc]; }
    if (tid < 128) s_w1[tid] = rw1[64 * 64 + tid];
    if (blockIdx.x == 0 && tid < 4) sumexp[tid] = 0.f;
    __syncthreads();
    int lane = tid & 63;
    int sub = lane >> 4, l16 = lane & 15;
    int gid = (blockIdx.x * blockDim.x + tid) >> 6;
    int c = gid * 4 + sub;
    if (c >= N_NODES) return;
    // per-lane weights for fixed channels ch = l16*4 + j
    float w1a[4], w1b[4], wr2[4][4];
    #pragma unroll
    for (int j = 0; j < 4; j++) {
        int ch = l16 * 4 + j;
        w1a[j] = s_w1[ch];
        w1b[j] = s_w1[64 + ch];
        #pragma unroll
        for (int o = 0; o < 4; o++) wr2[j][o] = s_rw2[ch][o];
    }
    float2 trS = *(const float2*)(t + (size_t)c * 64 + l16 * 4);
    float4 hv = ((const float4*)hb)[c * 16 + l16];
    float a0 = 0.f, a1 = 0.f, a2 = 0.f, a3 = 0.f;
    float b0 = 0.f, b1 = 0.f, b2 = 0.f, b3 = 0.f;
    {
        float tk[4];
        cvt_t4(trS, tk);
        #pragma unroll
        for (int j = 0; j < 4; j++) {
            int ch = l16 * 4 + j;
            float rr = fmaxf(tk[j], 0.f);   // self loop: ea = 0
            a0 += rr * wr2[j][0]; a1 += rr * wr2[j][1];
            a2 += rr * wr2[j][2]; a3 += rr * wr2[j][3];
            float hk = (j == 0) ? hv.x : (j == 1) ? hv.y : (j == 2) ? hv.z : hv.w;
            b0 += hk * s_sw[ch][0]; b1 += hk * s_sw[ch][1];
            b2 += hk * s_sw[ch][2]; b3 += hk * s_sw[ch][3];
        }
    }
    int cnt = (int)cntC[c];
    const uint2* rowE = colEA + (size_t)c * BUCKET;
    const uint2 zr = make_uint2(0u, 0u);
    const float2 z2 = make_float2(0.f, 0.f);
    int p = 0;
    bool vld0 = p < cnt;
    uint2 erA = vld0 ? rowE[0] : zr;
    float2 trA = vld0 ? *(const float2*)(t + (size_t)erA.y * 64 + l16 * 4) : z2;
    int pn = 1;
    bool vld1 = pn < cnt;
    uint2 erB = vld1 ? rowE[1] : zr;
    while (vld0) {
        float2 trB = vld1 ? *(const float2*)(t + (size_t)erB.y * 64 + l16 * 4) : z2;
        int pnn = pn + 1;
        bool vld2 = pnn < cnt;
        uint2 erC = vld2 ? rowE[pnn] : zr;
        float tk[4];
        cvt_t4(trA, tk);
        __half2 eh = *reinterpret_cast<const __half2*>(&erA.x);
        float2 ef = __half22float2(eh);
        float ex = ef.x, ey = ef.y;
        #pragma unroll
        for (int j = 0; j < 4; j++) {
            float pre = tk[j] + ex * w1a[j] + ey * w1b[j];
            float rr = fmaxf(pre, 0.f);
            a0 += rr * wr2[j][0]; a1 += rr * wr2[j][1];
            a2 += rr * wr2[j][2]; a3 += rr * wr2[j][3];
        }
        erA = erB; trA = trB; erB = erC;
        vld0 = vld1; vld1 = vld2; pn = pnn;
    }
    a0 = dpp_sum16(a0); a1 = dpp_sum16(a1); a2 = dpp_sum16(a2); a3 = dpp_sum16(a3);
    b0 = dpp_sum16(b0); b1 = dpp_sum16(b1); b2 = dpp_sum16(b2); b3 = dpp_sum16(b3);
    if (l16 == 0) {
        float idg = 1.f / (float)(cnt + 1);
        x4b[c] = make_float4(a0 * idg + b0 + rb2[0] + sb[0],
                             a1 * idg + b1 + rb2[1] + sb[1],
                             a2 * idg + b2 + rb2[2] + sb[2],
                             a3 * idg + b3 + rb2[3] + sb[3]);
    }
}

// attention gather, rank-4-factored V; WAVE per dst, 2-deep pipelined slot loop.
__global__ void k5_att(const unsigned* __restrict__ cntC, const uint2* __restrict__ colEA,
                       const float4* __restrict__ x4b, const float* __restrict__ cst,
                       const float* __restrict__ cstV, float* __restrict__ att16,
                       float* __restrict__ zbuf) {
    int tid = threadIdx.x;
    int lane = tid & 63;
    int sub = lane >> 4, d = lane & 15, h = d >> 2, a = d & 3;
    const float* C = cst + h * 32;
    int c = (blockIdx.x * blockDim.x + tid) >> 6;   // wave per dst
    if (c >= N_NODES) return;
    float4 xc = x4b[c];
    float g0 = xc.x * C[0]  + xc.y * C[1]  + xc.z * C[2]  + xc.w * C[3]  + C[16];
    float g1 = xc.x * C[4]  + xc.y * C[5]  + xc.z * C[6]  + xc.w * C[7]  + C[17];
    float g2 = xc.x * C[8]  + xc.y * C[9]  + xc.z * C[10] + xc.w * C[11] + C[18];
    float g3 = xc.x * C[12] + xc.y * C[13] + xc.z * C[14] + xc.w * C[15] + C[19];
    float base = C[20] * xc.x + C[21] * xc.y + C[22] * xc.z + C[23] * xc.w + C[24];
    int cnt = (int)cntC[c];
    const uint2* rowE = colEA + (size_t)c * BUCKET;
    float S = 0.f, z = 0.f;
    int p = sub;
    bool vld0 = p < cnt;
    float4 xr = make_float4(0.f, 0.f, 0.f, 0.f);
    if (vld0) xr = x4b[rowE[p].y];
    int pn = p + 4;
    bool vld1 = pn < cnt;
    unsigned rn = vld1 ? rowE[pn].y : 0u;
    while (vld0) {
        float4 xrn = make_float4(0.f, 0.f, 0.f, 0.f);
        if (vld1) xrn = x4b[rn];
        int pnn = pn + 4;
        bool vld2 = pnn < cnt;
        unsigned rnn = vld2 ? rowE[pnn].y : 0u;
        float s = xr.x * g0 + xr.y * g1 + xr.z * g2 + xr.w * g3 + base;
        float ex = __expf(s);
        float xa = (a == 0) ? xr.x : (a == 1) ? xr.y : (a == 2) ? xr.z : xr.w;
        S += ex * xa;
        z += ex;
        xr = xrn; rn = rnn; vld0 = vld1; vld1 = vld2; pn = pnn;
    }
    S += __shfl_xor(S, 16); S += __shfl_xor(S, 32);
    z += __shfl_xor(z, 16); z += __shfl_xor(z, 32);
    const float* V = cstV + h * 32;
    float c0 = S * V[a * 4 + 0], c1 = S * V[a * 4 + 1];
    float c2 = S * V[a * 4 + 2], c3 = S * V[a * 4 + 3];
    c0 = dpp_addf<DPP_QX1>(c0); c1 = dpp_addf<DPP_QX1>(c1);
    c2 = dpp_addf<DPP_QX1>(c2); c3 = dpp_addf<DPP_QX1>(c3);
    c0 = dpp_addf<DPP_QX2>(c0); c1 = dpp_addf<DPP_QX2>(c1);
    c2 = dpp_addf<DPP_QX2>(c2); c3 = dpp_addf<DPP_QX2>(c3);
    float my = (a == 0) ? c0 : (a == 1) ? c1 : (a == 2) ? c2 : c3;
    if (sub == 0) {
        att16[c * 16 + d] = my + z * V[16 + a];
        if (a == 0) zbuf[c * 4 + h] = z;
    }
}

// reduce zbuf (N_NODES x 4) -> sumexp[4]; LDS block reduction, 49 atomics per head
__global__ void __launch_bounds__(1024) k_zred(const float4* __restrict__ zbuf,
                                               float* __restrict__ sumexp) {
    __shared__ float s[16][4];
    int tid = threadIdx.x;
    int i = blockIdx.x * 1024 + tid;
    float4 v = make_float4(0.f, 0.f, 0.f, 0.f);
    if (i < N_NODES) v = zbuf[i];
    bsum4(v.x, v.y, v.z, v.w);
    int w = tid >> 6;
    if ((tid & 63) == 0) { s[w][0] = v.x; s[w][1] = v.y; s[w][2] = v.z; s[w][3] = v.w; }
    __syncthreads();
    if (tid < 4) {
        float acc = 0.f;
        #pragma unroll
        for (int ww = 0; ww < 16; ww++) acc += s[ww][tid];
        atomicAdd(&sumexp[tid], acc);
    }
}

// final: finalize layer 3 then MLP head (readlane GEMM)
__global__ void k6pred(const float* __restrict__ att16, const float* __restrict__ sumexp,
                       const float4* __restrict__ x4b, const float* __restrict__ ob,
                       const float* __restrict__ g, const float* __restrict__ bb,
                       const float* __restrict__ resw, const float4* __restrict__ xcur,
                       const float* __restrict__ in_w, const float* __restrict__ in_b,
                       const float* __restrict__ w1, const float* __restrict__ b1,
                       const float* __restrict__ w2, const float* __restrict__ b2,
                       float* __restrict__ out) {
    int tid = threadIdx.x;
    int node = (blockIdx.x * blockDim.x + tid) >> 6;
    int lane = tid & 63;
    if (node >= N_NODES) return;
    float z = sumexp[(lane & 15) >> 2];
    float a = 0.f;
    if (lane < 16) a = att16[node * 16 + lane] / z;
    a = dpp_addf<DPP_ROR4>(a);
    a = dpp_addf<DPP_ROR8>(a);
    float y0 = rdlane(a, 0), y1 = rdlane(a, 1), y2 = rdlane(a, 2), y3 = rdlane(a, 3);
    float4 x4v = x4b[node];
    y0 += ob[0] + x4v.x; y1 += ob[1] + x4v.y;
    y2 += ob[2] + x4v.z; y3 += ob[3] + x4v.w;
    float mu = 0.25f * (y0 + y1 + y2 + y3);
    float d0 = y0 - mu, d1 = y1 - mu, d2 = y2 - mu, d3 = y3 - mu;
    float var = 0.25f * (d0 * d0 + d1 * d1 + d2 * d2 + d3 * d3);
    float rs = rsqrtf(var + 1e-5f);
    float4 xold = xcur[node];
    float rw = resw[0];
    float n0 = d0 * rs * g[0] + bb[0] + xold.x * rw;
    float n1 = d1 * rs * g[1] + bb[1] + xold.y * rw;
    float n2 = d2 * rs * g[2] + bb[2] + xold.z * rw;
    float n3 = d3 * rs * g[3] + bb[3] + xold.w * rw;
    float hv = in_b[lane] + n0 * in_w[lane] + n1 * in_w[64 + lane]
             + n2 * in_w[128 + lane] + n3 * in_w[192 + lane];
    int j2 = lane & 31;
    float m = b1[j2];
    for (int k = 0; k < 64; k++) m += rdlane(hv, k) * w1[k * 32 + j2];
    m = fmaxf(m, 0.f);
    float4 w2v = ((const float4*)w2)[j2];
    float v0 = m * w2v.x, v1 = m * w2v.y, v2 = m * w2v.z, v3 = m * w2v.w;
    bsum4(v0, v1, v2, v3);  // each j2 counted twice (both halves) -> *0.5
    float o0 = tanhf(0.5f * v0 + b2[0]) * 0.3f;
    float o1 = tanhf(0.5f * v1 + b2[1]) * 0.3f;
    float o2 = tanhf(0.5f * v2 + b2[2]) * 0.3f;
    float o3 = tanhf(0.5f * v3 + b2[3]) * 0.3f;
    if (lane == 0) ((float4*)out)[node] = make_float4(o0, o1, o2, o3);
}

// ---------- launch ----------
extern "C" void kernel_launch(void* const* d_in, const int* in_sizes, int n_in,
                              void* d_out, int out_size, void* d_ws, size_t ws_size,
                              hipStream_t stream) {
    const float* x        = (const float*)d_in[0];
    const int*   ei       = (const int*)d_in[1];
    const float* ea       = (const float*)d_in[2];
    const float* in_w     = (const float*)d_in[3];
    const float* in_b     = (const float*)d_in[4];
    const float* conv_rw1 = (const float*)d_in[5];
    const float* conv_rb1 = (const float*)d_in[6];
    const float* conv_rw2 = (const float*)d_in[7];
    const float* conv_rb2 = (const float*)d_in[8];
    // d_in[9..12] (imag path) dead: x4 = h4[:, :4] only touches real[:, :4]
    const float* conv_sw  = (const float*)d_in[13];
    const float* conv_sb  = (const float*)d_in[14];
    const float* att_qw   = (const float*)d_in[15];
    const float* att_qb   = (const float*)d_in[16];
    const float* att_kw   = (const float*)d_in[17];
    const float* att_kb   = (const float*)d_in[18];
    const float* att_vw   = (const float*)d_in[19];
    const float* att_vb   = (const float*)d_in[20];
    const float* att_ow   = (const float*)d_in[21];
    const float* att_ob   = (const float*)d_in[22];
    const float* ln_g     = (const float*)d_in[23];
    const float* ln_b     = (const float*)d_in[24];
    const float* out_w1   = (const float*)d_in[25];
    const float* out_b1   = (const float*)d_in[26];
    const float* out_w2   = (const float*)d_in[27];
    const float* out_b2   = (const float*)d_in[28];
    const float* res_w    = (const float*)d_in[29];

    const int* row = ei;
    const int* col = ei + N_EDGES;

    char* ws = (char*)d_ws;
    size_t off = 0;
    auto alloc = [&](size_t bytes) -> void* {
        void* p = ws + off;
        off = (off + bytes + 255) & ~(size_t)255;
        return p;
    };
    unsigned* cntC     = (unsigned*)alloc(N_NODES * 4);
    uint2*    colEA    = (uint2*)alloc((size_t)N_NODES * BUCKET * 8);
    __half*   tbuf     = (__half*)alloc((size_t)N_NODES * 64 * 2);
    float*    hb       = (float*)alloc((size_t)N_NODES * 64 * 4);
    float*    att16    = (float*)alloc((size_t)N_NODES * 16 * 4);
    float*    zbuf     = (float*)alloc((size_t)N_NODES * 4 * 4);
    float4*   x4b      = (float4*)alloc((size_t)N_NODES * 16);
    float4*   xcur     = (float4*)alloc((size_t)N_NODES * 16);
    float*    cst      = (float*)alloc(4 * 128 * 4);
    float*    cstV     = (float*)alloc(4 * 128 * 4);
    float*    sumexp   = (float*)alloc(256);

    dim3 b256(256);
    int nodeBlocks  = (N_NODES + 3) / 4;        // wave per node
    int nodeBlocks4 = (N_NODES + 15) / 16;      // wave per 4 nodes
    int dstBlocks   = (N_NODES + 15) / 16;      // quarter-wave per dst
    int zredBlocks  = (N_NODES + 1023) / 1024;

    hipMemsetAsync(cntC, 0, N_NODES * 4, stream);
    k_setup<<<EDGE_TB + NODE_NB + 8, b256, 0, stream>>>(
        x, in_w, in_b, conv_rw1, conv_rb1, hb, xcur, cntC, tbuf,
        row, col, ea, colEA,
        att_qw, att_qb, att_kw, att_kb, att_vw, att_vb, att_ow, cst, cstV);

    for (int i = 0; i < 4; i++) {
        const float* rw1 = conv_rw1 + i * 66 * 64;
        const float* rb1 = conv_rb1 + i * 64;
        const float* rw2 = conv_rw2 + i * 64 * 64;
        const float* rb2 = conv_rb2 + i * 64;
        const float* swl = conv_sw + i * 64 * 256;
        const float* sbl = conv_sb + i * 256;

        if (i > 0) {
            k61<<<nodeBlocks4, b256, 0, stream>>>(att16, sumexp, x4b,
                                                  att_ob + (i - 1) * 4, ln_g + (i - 1) * 4,
                                                  ln_b + (i - 1) * 4, res_w + (i - 1),
                                                  in_w, in_b, xcur,
                                                  rw1, rb1, tbuf, hb);
        }
        k23b<<<dstBlocks, b256, 0, stream>>>(cntC, colEA, tbuf, hb,
                                             rw1, rw2, swl, rb2, sbl, x4b, sumexp);
        k5_att<<<nodeBlocks, b256, 0, stream>>>(cntC, colEA, x4b, cst + i * 128,
                                                cstV + i * 128, att16, zbuf);
        k_zred<<<zredBlocks, 1024, 0, stream>>>((const float4*)zbuf, sumexp);
    }
    k6pred<<<nodeBlocks, b256, 0, stream>>>(att16, sumexp, x4b, att_ob + 12, ln_g + 12,
                                            ln_b + 12, res_w + 3, xcur, in_w, in_b,
                                            out_w1, out_b1, out_w2, out_b2, (float*)d_out);
}

// Round 7
// 526.824 us; speedup vs baseline: 1.4058x; 1.0472x over previous
//
#include <hip/hip_runtime.h>
#include <hip/hip_bf16.h>
#include <hip/hip_fp16.h>

#define N_NODES 50000
#define N_EDGES 800000
#define BUCKET 64   // per-dst edge capacity; deg ~ Poisson(16), P(>64) ~ 1e-18
#define EDGE_TB 3125   // (N_EDGES+255)/256
#define NODE_NB 3125   // (N_NODES+15)/16  (== EDGE_TB -> exact parity pairing)

// ---------- helpers ----------
__device__ __forceinline__ float rdlane(float v, int k) {
    return __uint_as_float(__builtin_amdgcn_readlane(__float_as_uint(v), k));
}
template <int CTRL>
__device__ __forceinline__ float dpp_addf(float v) {
    int x = __builtin_amdgcn_update_dpp(0, __float_as_int(v), CTRL, 0xF, 0xF, true);
    return v + __int_as_float(x);
}
#define DPP_QX1  0xB1   // quad_perm [1,0,3,2]
#define DPP_QX2  0x4E   // quad_perm [2,3,0,1]
#define DPP_HM   0x141  // row_half_mirror
#define DPP_RM   0x140  // row_mirror
#define DPP_ROR4 0x124  // row_ror:4
#define DPP_ROR8 0x128  // row_ror:8
__device__ __forceinline__ float dpp_sum16(float v) {
    v = dpp_addf<DPP_QX1>(v);
    v = dpp_addf<DPP_QX2>(v);
    v = dpp_addf<DPP_HM>(v);
    v = dpp_addf<DPP_RM>(v);
    return v;
}
__device__ __forceinline__ void bsum4(float& v0, float& v1, float& v2, float& v3) {
    #pragma unroll
    for (int m = 1; m < 64; m <<= 1) {
        v0 += __shfl_xor(v0, m);
        v1 += __shfl_xor(v1, m);
        v2 += __shfl_xor(v2, m);
        v3 += __shfl_xor(v3, m);
    }
}
// convert 4 packed halves (loaded as float2) to 4 floats
__device__ __forceinline__ void cvt_t4(float2 raw, float tk[4]) {
    __half2 a = ((const __half2*)&raw)[0];
    __half2 b = ((const __half2*)&raw)[1];
    float2 fa = __half22float2(a), fb = __half22float2(b);
    tk[0] = fa.x; tk[1] = fa.y; tk[2] = fb.x; tk[3] = fb.y;
}

// ---------- fused setup ----------
// PARITY-INTERLEAVED: even blocks = edge scatter (latency-bound, idle VALU),
// odd blocks = node init (VALU-bound) -> resident mix on every CU from t=0.
// Last 8 blocks: attention constant prep. cntC zeroed by memset.
__global__ void k_setup(const float* __restrict__ x, const float* __restrict__ in_w,
                        const float* __restrict__ in_b, const float* __restrict__ rw1,
                        const float* __restrict__ rb1, float* __restrict__ hb,
                        float4* __restrict__ xcur, unsigned* __restrict__ cntC,
                        __half* __restrict__ t,
                        const int* __restrict__ row, const int* __restrict__ col,
                        const float* __restrict__ ea, uint2* __restrict__ colEA,
                        const float* __restrict__ qw, const float* __restrict__ qb,
                        const float* __restrict__ kw, const float* __restrict__ kb,
                        const float* __restrict__ vw, const float* __restrict__ vb,
                        const float* __restrict__ ow, float* __restrict__ cst,
                        float* __restrict__ cstV) {
    int tid = threadIdx.x;
    int bid = blockIdx.x;
    if (bid < 2 * EDGE_TB) {
        if ((bid & 1) == 0) {
            // ---- edge scatter: 8B record {half2 ea, src} ----
            int e = (bid >> 1) * 256 + tid;
            if (e < N_EDGES) {
                int c = col[e];
                unsigned slot = atomicAdd(&cntC[c], 1u);
                float2 e2 = ((const float2*)ea)[e];
                __half2 h2 = __floats2half2_rn(e2.x, e2.y);
                colEA[(size_t)c * BUCKET + slot] =
                    make_uint2(*reinterpret_cast<unsigned*>(&h2), (unsigned)row[e]);
            }
            return;
        }
        // ---- node init: h, xcur, layer-0 t ----
        int wid = ((bid >> 1) * 256 + tid) >> 6;
        int lane = tid & 63;
        int n0 = wid * 4;
        if (n0 >= N_NODES) return;
        float iw0 = in_w[lane], iw1 = in_w[64 + lane], iw2 = in_w[128 + lane], iw3 = in_w[192 + lane];
        float ibl = in_b[lane];
        float hv[4];
        #pragma unroll
        for (int i = 0; i < 4; i++) {
            int n = n0 + i;
            hv[i] = 0.f;
            if (n < N_NODES) {
                float4 xv = ((const float4*)x)[n];
                hv[i] = ibl + xv.x * iw0 + xv.y * iw1 + xv.z * iw2 + xv.w * iw3;
                hb[n * 64 + lane] = hv[i];
                if (lane == 0) xcur[n] = xv;
            }
        }
        float acc[4];
        #pragma unroll
        for (int i = 0; i < 4; i++) acc[i] = rb1[lane];
        for (int k = 0; k < 64; k++) {
            float w = rw1[k * 64 + lane];
            #pragma unroll
            for (int i = 0; i < 4; i++) acc[i] += rdlane(hv[i], k) * w;
        }
        #pragma unroll
        for (int i = 0; i < 4; i++) {
            int n = n0 + i;
            if (n < N_NODES) t[n * 64 + lane] = __float2half(acc[i]);
        }
        return;
    }
    // ---- attention constant prep (8 logical blocks, 64 threads used) ----
    int pb = bid - 2 * EDGE_TB;
    int m = tid;
    if (m >= 64) return;
    int d = m & 15;
    if (pb < 4) {
        int L = pb;
        const float* qwl = qw + L * 256; const float* kwl = kw + L * 256;
        const float* qbl = qb + L * 64;  const float* kbl = kb + L * 64;
        float qa[4], ka[4];
        #pragma unroll
        for (int a = 0; a < 4; a++) { qa[a] = qwl[a * 64 + m]; ka[a] = kwl[a * 64 + m]; }
        float qbm = qbl[m], kbm = kbl[m];
        float vals[25];
        int idx = 0;
        #pragma unroll
        for (int a = 0; a < 4; a++)
            #pragma unroll
            for (int b = 0; b < 4; b++) vals[idx++] = qa[a] * ka[b];
        #pragma unroll
        for (int a = 0; a < 4; a++) vals[idx++] = qa[a] * kbm;
        #pragma unroll
        for (int b = 0; b < 4; b++) vals[idx++] = qbm * ka[b];
        vals[24] = qbm * kbm;
        #pragma unroll
        for (int i = 0; i < 25; i++) {
            float v = vals[i];
            v += __shfl_xor(v, 1); v += __shfl_xor(v, 2);
            v += __shfl_xor(v, 4); v += __shfl_xor(v, 8);
            vals[i] = v;
        }
        if (d == 0) {
            float* out = cst + L * 128 + (m >> 4) * 32;
            #pragma unroll
            for (int i = 0; i < 25; i++) out[i] = vals[i] * 0.25f;
        }
    } else {
        int L = pb - 4;
        int h = m >> 4;
        const float* vwl = vw + L * 256;
        const float* vbl = vb + L * 64;
        float4 owv = ((const float4*)(ow + L * 256))[m];
        float vals[20];
        #pragma unroll
        for (int a = 0; a < 4; a++) {
            float v = vwl[a * 64 + m];
            vals[a * 4 + 0] = v * owv.x; vals[a * 4 + 1] = v * owv.y;
            vals[a * 4 + 2] = v * owv.z; vals[a * 4 + 3] = v * owv.w;
        }
        float b = vbl[m];
        vals[16] = b * owv.x; vals[17] = b * owv.y; vals[18] = b * owv.z; vals[19] = b * owv.w;
        #pragma unroll
        for (int i = 0; i < 20; i++) {
            float v = vals[i];
            v += __shfl_xor(v, 1); v += __shfl_xor(v, 2);
            v += __shfl_xor(v, 4); v += __shfl_xor(v, 8);
            vals[i] = v;
        }
        if (d == 0) {
            float* out = cstV + L * 128 + h * 32;
            #pragma unroll
            for (int i = 0; i < 20; i++) out[i] = vals[i];
        }
    }
}

// ---------- per-layer ----------
// layers 1..3: finalize prev layer, write h, compute this layer's t (readlane GEMM)
// sumexpP: 64x4 partial z sums -> reduced in-register via bsum4 (replaces k_zred)
__global__ void k61(const float* __restrict__ att16, const float* __restrict__ sumexpP,
                    const float4* __restrict__ x4b, const float* __restrict__ ob,
                    const float* __restrict__ g, const float* __restrict__ bb,
                    const float* __restrict__ resw, const float* __restrict__ in_w,
                    const float* __restrict__ in_b, float4* __restrict__ xcur,
                    const float* __restrict__ rw1, const float* __restrict__ rb1,
                    __half* __restrict__ t, float* __restrict__ hb) {
    int tid = threadIdx.x;
    int wid = (blockIdx.x * blockDim.x + tid) >> 6;
    int lane = tid & 63;
    int n0 = wid * 4;
    if (n0 >= N_NODES) return;
    float iw0 = in_w[lane], iw1 = in_w[64 + lane], iw2 = in_w[128 + lane], iw3 = in_w[192 + lane];
    float ibl = in_b[lane];
    // global z per head: sum the 64x4 partial array across the wave
    float4 zp = ((const float4*)sumexpP)[lane];
    bsum4(zp.x, zp.y, zp.z, zp.w);
    int hh = (lane & 15) >> 2;
    float z = (hh == 0) ? zp.x : (hh == 1) ? zp.y : (hh == 2) ? zp.z : zp.w;
    float ob0 = ob[0], ob1 = ob[1], ob2 = ob[2], ob3 = ob[3];
    float g0 = g[0], g1 = g[1], g2 = g[2], g3 = g[3];
    float bb0 = bb[0], bb1 = bb[1], bb2 = bb[2], bb3 = bb[3];
    float rw = resw[0];
    float hv[4];
    #pragma unroll
    for (int i = 0; i < 4; i++) {
        int n = n0 + i;
        float a = 0.f;
        if (n < N_NODES && lane < 16) a = att16[n * 16 + lane] / z;
        a = dpp_addf<DPP_ROR4>(a);
        a = dpp_addf<DPP_ROR8>(a);
        float y0 = rdlane(a, 0), y1 = rdlane(a, 1), y2 = rdlane(a, 2), y3 = rdlane(a, 3);
        hv[i] = 0.f;
        if (n < N_NODES) {
            float4 x4v = x4b[n];
            y0 += ob0 + x4v.x; y1 += ob1 + x4v.y;
            y2 += ob2 + x4v.z; y3 += ob3 + x4v.w;
            float mu = 0.25f * (y0 + y1 + y2 + y3);
            float d0 = y0 - mu, d1 = y1 - mu, d2 = y2 - mu, d3 = y3 - mu;
            float var = 0.25f * (d0 * d0 + d1 * d1 + d2 * d2 + d3 * d3);
            float rs = rsqrtf(var + 1e-5f);
            float4 xold = xcur[n];
            float nn0 = d0 * rs * g0 + bb0 + xold.x * rw;
            float nn1 = d1 * rs * g1 + bb1 + xold.y * rw;
            float nn2 = d2 * rs * g2 + bb2 + xold.z * rw;
            float nn3 = d3 * rs * g3 + bb3 + xold.w * rw;
            if (lane == 0) xcur[n] = make_float4(nn0, nn1, nn2, nn3);
            hv[i] = ibl + nn0 * iw0 + nn1 * iw1 + nn2 * iw2 + nn3 * iw3;
            hb[n * 64 + lane] = hv[i];
        }
    }
    float acc[4];
    #pragma unroll
    for (int i = 0; i < 4; i++) acc[i] = rb1[lane];
    for (int k = 0; k < 64; k++) {
        float w = rw1[k * 64 + lane];
        #pragma unroll
        for (int i = 0; i < 4; i++) acc[i] += rdlane(hv[i], k) * w;
    }
    #pragma unroll
    for (int i = 0; i < 4; i++) {
        int n = n0 + i;
        if (n < N_NODES) t[n * 64 + lane] = __float2half(acc[i]);
    }
}

// fused msg-compute + gather + self-loop + base + x4: quarter-wave per dst.
// fp16 t rows (8B/lane), 8B records {half2 ea, src}.
// block 0 also zeroes the sumexpP partials for this layer's k5_att.
__global__ void k23b(const unsigned* __restrict__ cntC, const uint2* __restrict__ colEA,
                     const __half* __restrict__ t, const float* __restrict__ hb,
                     const float* __restrict__ rw1, const float* __restrict__ rw2,
                     const float* __restrict__ sw, const float* __restrict__ rb2,
                     const float* __restrict__ sb,
                     float4* __restrict__ x4b, float* __restrict__ sumexpP) {
    __shared__ float s_rw2[64][4];
    __shared__ float s_sw[64][4];
    __shared__ float s_w1[128];
    int tid = threadIdx.x;
    { int r = tid >> 2, cc = tid & 3; s_rw2[r][cc] = rw2[r * 64 + cc]; s_sw[r][cc] = sw[r * 256 + cc]; }
    if (tid < 128) s_w1[tid] = rw1[64 * 64 + tid];
    if (blockIdx.x == 0) sumexpP[tid] = 0.f;
    __syncthreads();
    int lane = tid & 63;
    int sub = lane >> 4, l16 = lane & 15;
    int gid = (blockIdx.x * blockDim.x + tid) >> 6;
    int c = gid * 4 + sub;
    if (c >= N_NODES) return;
    // per-lane weights for fixed channels ch = l16*4 + j
    float w1a[4], w1b[4], wr2[4][4];
    #pragma unroll
    for (int j = 0; j < 4; j++) {
        int ch = l16 * 4 + j;
        w1a[j] = s_w1[ch];
        w1b[j] = s_w1[64 + ch];
        #pragma unroll
        for (int o = 0; o < 4; o++) wr2[j][o] = s_rw2[ch][o];
    }
    float2 trS = *(const float2*)(t + (size_t)c * 64 + l16 * 4);
    float4 hv = ((const float4*)hb)[c * 16 + l16];
    float a0 = 0.f, a1 = 0.f, a2 = 0.f, a3 = 0.f;
    float b0 = 0.f, b1 = 0.f, b2 = 0.f, b3 = 0.f;
    {
        float tk[4];
        cvt_t4(trS, tk);
        #pragma unroll
        for (int j = 0; j < 4; j++) {
            int ch = l16 * 4 + j;
            float rr = fmaxf(tk[j], 0.f);   // self loop: ea = 0
            a0 += rr * wr2[j][0]; a1 += rr * wr2[j][1];
            a2 += rr * wr2[j][2]; a3 += rr * wr2[j][3];
            float hk = (j == 0) ? hv.x : (j == 1) ? hv.y : (j == 2) ? hv.z : hv.w;
            b0 += hk * s_sw[ch][0]; b1 += hk * s_sw[ch][1];
            b2 += hk * s_sw[ch][2]; b3 += hk * s_sw[ch][3];
        }
    }
    int cnt = (int)cntC[c];
    const uint2* rowE = colEA + (size_t)c * BUCKET;
    const uint2 zr = make_uint2(0u, 0u);
    const float2 z2 = make_float2(0.f, 0.f);
    int p = 0;
    bool vld0 = p < cnt;
    uint2 erA = vld0 ? rowE[0] : zr;
    float2 trA = vld0 ? *(const float2*)(t + (size_t)erA.y * 64 + l16 * 4) : z2;
    int pn = 1;
    bool vld1 = pn < cnt;
    uint2 erB = vld1 ? rowE[1] : zr;
    while (vld0) {
        float2 trB = vld1 ? *(const float2*)(t + (size_t)erB.y * 64 + l16 * 4) : z2;
        int pnn = pn + 1;
        bool vld2 = pnn < cnt;
        uint2 erC = vld2 ? rowE[pnn] : zr;
        float tk[4];
        cvt_t4(trA, tk);
        __half2 eh = *reinterpret_cast<const __half2*>(&erA.x);
        float2 ef = __half22float2(eh);
        float ex = ef.x, ey = ef.y;
        #pragma unroll
        for (int j = 0; j < 4; j++) {
            float pre = tk[j] + ex * w1a[j] + ey * w1b[j];
            float rr = fmaxf(pre, 0.f);
            a0 += rr * wr2[j][0]; a1 += rr * wr2[j][1];
            a2 += rr * wr2[j][2]; a3 += rr * wr2[j][3];
        }
        erA = erB; trA = trB; erB = erC;
        vld0 = vld1; vld1 = vld2; pn = pnn;
    }
    a0 = dpp_sum16(a0); a1 = dpp_sum16(a1); a2 = dpp_sum16(a2); a3 = dpp_sum16(a3);
    b0 = dpp_sum16(b0); b1 = dpp_sum16(b1); b2 = dpp_sum16(b2); b3 = dpp_sum16(b3);
    if (l16 == 0) {
        float idg = 1.f / (float)(cnt + 1);
        x4b[c] = make_float4(a0 * idg + b0 + rb2[0] + sb[0],
                             a1 * idg + b1 + rb2[1] + sb[1],
                             a2 * idg + b2 + rb2[2] + sb[2],
                             a3 * idg + b3 + rb2[3] + sb[3]);
    }
}

// attention gather, rank-4-factored V; WAVE per dst, 2-deep pipelined slot loop.
// z-sum: block LDS reduce -> 4 atomics into 64-way-split partials (k_zred deleted).
__global__ void k5_att(const unsigned* __restrict__ cntC, const uint2* __restrict__ colEA,
                       const float4* __restrict__ x4b, const float* __restrict__ cst,
                       const float* __restrict__ cstV, float* __restrict__ att16,
                       float* __restrict__ sumexpP) {
    __shared__ float zs[4][4];
    int tid = threadIdx.x;
    int lane = tid & 63;
    int wv = tid >> 6;
    int sub = lane >> 4, d = lane & 15, h = d >> 2, a = d & 3;
    int c = (blockIdx.x * blockDim.x + tid) >> 6;   // wave per dst
    float zval = 0.f;
    if (c < N_NODES) {
        const float* C = cst + h * 32;
        float4 xc = x4b[c];
        float g0 = xc.x * C[0]  + xc.y * C[1]  + xc.z * C[2]  + xc.w * C[3]  + C[16];
        float g1 = xc.x * C[4]  + xc.y * C[5]  + xc.z * C[6]  + xc.w * C[7]  + C[17];
        float g2 = xc.x * C[8]  + xc.y * C[9]  + xc.z * C[10] + xc.w * C[11] + C[18];
        float g3 = xc.x * C[12] + xc.y * C[13] + xc.z * C[14] + xc.w * C[15] + C[19];
        float base = C[20] * xc.x + C[21] * xc.y + C[22] * xc.z + C[23] * xc.w + C[24];
        int cnt = (int)cntC[c];
        const uint2* rowE = colEA + (size_t)c * BUCKET;
        float S = 0.f, z = 0.f;
        int p = sub;
        bool vld0 = p < cnt;
        float4 xr = make_float4(0.f, 0.f, 0.f, 0.f);
        if (vld0) xr = x4b[rowE[p].y];
        int pn = p + 4;
        bool vld1 = pn < cnt;
        unsigned rn = vld1 ? rowE[pn].y : 0u;
        while (vld0) {
            float4 xrn = make_float4(0.f, 0.f, 0.f, 0.f);
            if (vld1) xrn = x4b[rn];
            int pnn = pn + 4;
            bool vld2 = pnn < cnt;
            unsigned rnn = vld2 ? rowE[pnn].y : 0u;
            float s = xr.x * g0 + xr.y * g1 + xr.z * g2 + xr.w * g3 + base;
            float ex = __expf(s);
            float xa = (a == 0) ? xr.x : (a == 1) ? xr.y : (a == 2) ? xr.z : xr.w;
            S += ex * xa;
            z += ex;
            xr = xrn; rn = rnn; vld0 = vld1; vld1 = vld2; pn = pnn;
        }
        S += __shfl_xor(S, 16); S += __shfl_xor(S, 32);
        z += __shfl_xor(z, 16); z += __shfl_xor(z, 32);
        const float* V = cstV + h * 32;
        float c0 = S * V[a * 4 + 0], c1 = S * V[a * 4 + 1];
        float c2 = S * V[a * 4 + 2], c3 = S * V[a * 4 + 3];
        c0 = dpp_addf<DPP_QX1>(c0); c1 = dpp_addf<DPP_QX1>(c1);
        c2 = dpp_addf<DPP_QX1>(c2); c3 = dpp_addf<DPP_QX1>(c3);
        c0 = dpp_addf<DPP_QX2>(c0); c1 = dpp_addf<DPP_QX2>(c1);
        c2 = dpp_addf<DPP_QX2>(c2); c3 = dpp_addf<DPP_QX2>(c3);
        float my = (a == 0) ? c0 : (a == 1) ? c1 : (a == 2) ? c2 : c3;
        if (sub == 0) att16[c * 16 + d] = my + z * V[16 + a];
        zval = z;
    }
    if (sub == 0 && a == 0) zs[wv][h] = zval;
    __syncthreads();
    if (tid < 4) {
        float acc = zs[0][tid] + zs[1][tid] + zs[2][tid] + zs[3][tid];
        atomicAdd(&sumexpP[((blockIdx.x & 63) << 2) + tid], acc);
    }
}

// final: finalize layer 3 then MLP head (readlane GEMM)
__global__ void k6pred(const float* __restrict__ att16, const float* __restrict__ sumexpP,
                       const float4* __restrict__ x4b, const float* __restrict__ ob,
                       const float* __restrict__ g, const float* __restrict__ bb,
                       const float* __restrict__ resw, const float4* __restrict__ xcur,
                       const float* __restrict__ in_w, const float* __restrict__ in_b,
                       const float* __restrict__ w1, const float* __restrict__ b1,
                       const float* __restrict__ w2, const float* __restrict__ b2,
                       float* __restrict__ out) {
    int tid = threadIdx.x;
    int node = (blockIdx.x * blockDim.x + tid) >> 6;
    int lane = tid & 63;
    if (node >= N_NODES) return;
    float4 zp = ((const float4*)sumexpP)[lane];
    bsum4(zp.x, zp.y, zp.z, zp.w);
    int hh = (lane & 15) >> 2;
    float z = (hh == 0) ? zp.x : (hh == 1) ? zp.y : (hh == 2) ? zp.z : zp.w;
    float a = 0.f;
    if (lane < 16) a = att16[node * 16 + lane] / z;
    a = dpp_addf<DPP_ROR4>(a);
    a = dpp_addf<DPP_ROR8>(a);
    float y0 = rdlane(a, 0), y1 = rdlane(a, 1), y2 = rdlane(a, 2), y3 = rdlane(a, 3);
    float4 x4v = x4b[node];
    y0 += ob[0] + x4v.x; y1 += ob[1] + x4v.y;
    y2 += ob[2] + x4v.z; y3 += ob[3] + x4v.w;
    float mu = 0.25f * (y0 + y1 + y2 + y3);
    float d0 = y0 - mu, d1 = y1 - mu, d2 = y2 - mu, d3 = y3 - mu;
    float var = 0.25f * (d0 * d0 + d1 * d1 + d2 * d2 + d3 * d3);
    float rs = rsqrtf(var + 1e-5f);
    float4 xold = xcur[node];
    float rw = resw[0];
    float n0 = d0 * rs * g[0] + bb[0] + xold.x * rw;
    float n1 = d1 * rs * g[1] + bb[1] + xold.y * rw;
    float n2 = d2 * rs * g[2] + bb[2] + xold.z * rw;
    float n3 = d3 * rs * g[3] + bb[3] + xold.w * rw;
    float hv = in_b[lane] + n0 * in_w[lane] + n1 * in_w[64 + lane]
             + n2 * in_w[128 + lane] + n3 * in_w[192 + lane];
    int j2 = lane & 31;
    float m = b1[j2];
    for (int k = 0; k < 64; k++) m += rdlane(hv, k) * w1[k * 32 + j2];
    m = fmaxf(m, 0.f);
    float4 w2v = ((const float4*)w2)[j2];
    float v0 = m * w2v.x, v1 = m * w2v.y, v2 = m * w2v.z, v3 = m * w2v.w;
    bsum4(v0, v1, v2, v3);  // each j2 counted twice (both halves) -> *0.5
    float o0 = tanhf(0.5f * v0 + b2[0]) * 0.3f;
    float o1 = tanhf(0.5f * v1 + b2[1]) * 0.3f;
    float o2 = tanhf(0.5f * v2 + b2[2]) * 0.3f;
    float o3 = tanhf(0.5f * v3 + b2[3]) * 0.3f;
    if (lane == 0) ((float4*)out)[node] = make_float4(o0, o1, o2, o3);
}

// ---------- launch ----------
extern "C" void kernel_launch(void* const* d_in, const int* in_sizes, int n_in,
                              void* d_out, int out_size, void* d_ws, size_t ws_size,
                              hipStream_t stream) {
    const float* x        = (const float*)d_in[0];
    const int*   ei       = (const int*)d_in[1];
    const float* ea       = (const float*)d_in[2];
    const float* in_w     = (const float*)d_in[3];
    const float* in_b     = (const float*)d_in[4];
    const float* conv_rw1 = (const float*)d_in[5];
    const float* conv_rb1 = (const float*)d_in[6];
    const float* conv_rw2 = (const float*)d_in[7];
    const float* conv_rb2 = (const float*)d_in[8];
    // d_in[9..12] (imag path) dead: x4 = h4[:, :4] only touches real[:, :4]
    const float* conv_sw  = (const float*)d_in[13];
    const float* conv_sb  = (const float*)d_in[14];
    const float* att_qw   = (const float*)d_in[15];
    const float* att_qb   = (const float*)d_in[16];
    const float* att_kw   = (const float*)d_in[17];
    const float* att_kb   = (const float*)d_in[18];
    const float* att_vw   = (const float*)d_in[19];
    const float* att_vb   = (const float*)d_in[20];
    const float* att_ow   = (const float*)d_in[21];
    const float* att_ob   = (const float*)d_in[22];
    const float* ln_g     = (const float*)d_in[23];
    const float* ln_b     = (const float*)d_in[24];
    const float* out_w1   = (const float*)d_in[25];
    const float* out_b1   = (const float*)d_in[26];
    const float* out_w2   = (const float*)d_in[27];
    const float* out_b2   = (const float*)d_in[28];
    const float* res_w    = (const float*)d_in[29];

    const int* row = ei;
    const int* col = ei + N_EDGES;

    char* ws = (char*)d_ws;
    size_t off = 0;
    auto alloc = [&](size_t bytes) -> void* {
        void* p = ws + off;
        off = (off + bytes + 255) & ~(size_t)255;
        return p;
    };
    unsigned* cntC     = (unsigned*)alloc(N_NODES * 4);
    uint2*    colEA    = (uint2*)alloc((size_t)N_NODES * BUCKET * 8);
    __half*   tbuf     = (__half*)alloc((size_t)N_NODES * 64 * 2);
    float*    hb       = (float*)alloc((size_t)N_NODES * 64 * 4);
    float*    att16    = (float*)alloc((size_t)N_NODES * 16 * 4);
    float4*   x4b      = (float4*)alloc((size_t)N_NODES * 16);
    float4*   xcur     = (float4*)alloc((size_t)N_NODES * 16);
    float*    cst      = (float*)alloc(4 * 128 * 4);
    float*    cstV     = (float*)alloc(4 * 128 * 4);
    float*    sumexpP  = (float*)alloc(64 * 4 * 4);   // 64-way-split z partials

    dim3 b256(256);
    int nodeBlocks  = (N_NODES + 3) / 4;        // wave per node
    int nodeBlocks4 = (N_NODES + 15) / 16;      // wave per 4 nodes
    int dstBlocks   = (N_NODES + 15) / 16;      // quarter-wave per dst

    hipMemsetAsync(cntC, 0, N_NODES * 4, stream);
    k_setup<<<2 * EDGE_TB + 8, b256, 0, stream>>>(
        x, in_w, in_b, conv_rw1, conv_rb1, hb, xcur, cntC, tbuf,
        row, col, ea, colEA,
        att_qw, att_qb, att_kw, att_kb, att_vw, att_vb, att_ow, cst, cstV);

    for (int i = 0; i < 4; i++) {
        const float* rw1 = conv_rw1 + i * 66 * 64;
        const float* rb1 = conv_rb1 + i * 64;
        const float* rw2 = conv_rw2 + i * 64 * 64;
        const float* rb2 = conv_rb2 + i * 64;
        const float* swl = conv_sw + i * 64 * 256;
        const float* sbl = conv_sb + i * 256;

        if (i > 0) {
            k61<<<nodeBlocks4, b256, 0, stream>>>(att16, sumexpP, x4b,
                                                  att_ob + (i - 1) * 4, ln_g + (i - 1) * 4,
                                                  ln_b + (i - 1) * 4, res_w + (i - 1),
                                                  in_w, in_b, xcur,
                                                  rw1, rb1, tbuf, hb);
        }
        k23b<<<dstBlocks, b256, 0, stream>>>(cntC, colEA, tbuf, hb,
                                             rw1, rw2, swl, rb2, sbl, x4b, sumexpP);
        k5_att<<<nodeBlocks, b256, 0, stream>>>(cntC, colEA, x4b, cst + i * 128,
                                                cstV + i * 128, att16, sumexpP);
    }
    k6pred<<<nodeBlocks, b256, 0, stream>>>(att16, sumexpP, x4b, att_ob + 12, ln_g + 12,
                                            ln_b + 12, res_w + 3, xcur, in_w, in_b,
                                            out_w1, out_b1, out_w2, out_b2, (float*)d_out);
}